// Round 4
// baseline (18587.785 us; speedup 1.0000x reference)
//
#include <hip/hip_runtime.h>
#include <math.h>

#define BB 512
#define HH 512
#define SS 256
#define XD0 3
#define TDN 256
#define FC1N 20
#define OUTN 2
#define TM 32
#define TN 32
#define TK 32
#define NBLK 256   // persistent grid size (== #CUs; 1 block/CU guaranteed co-resident)

typedef __attribute__((ext_vector_type(8))) short short8;
typedef __attribute__((ext_vector_type(4))) short short4v;
typedef __attribute__((ext_vector_type(4))) float f32x4;

__device__ __forceinline__ unsigned short bf16_rne(float f) {
    unsigned u = __float_as_uint(f);
    u += 0x7FFFu + ((u >> 16) & 1u);
    return (unsigned short)(u >> 16);
}
__device__ __forceinline__ float bf16_to_f(unsigned short h) {
    return __uint_as_float(((unsigned)h) << 16);
}
__device__ __forceinline__ float sigmoid_(float x) { return 1.0f / (1.0f + __expf(-x)); }
__device__ __forceinline__ float tanh_(float x) {
    float e = __expf(2.0f * x);
    return 1.0f - 2.0f / (e + 1.0f);
}

// ---- weights fp32 [4H][H] -> MFMA B-frag layout [jt32][g4][kt16][lane64][e8], hi+lo split
__global__ __launch_bounds__(256)
void cvt_wfrag(const float* __restrict__ W, short* __restrict__ hi, short* __restrict__ lo)
{
    int idx = blockIdx.x * 256 + threadIdx.x;   // 0..131071
    int l   = idx & 63;
    int kt  = (idx >> 6) & 15;
    int g   = (idx >> 10) & 3;
    int jt  = idx >> 12;
    int row = g * HH + jt * 16 + (l & 15);
    int col = kt * 32 + (l >> 4) * 8;
    size_t src = (size_t)row * HH + col;
    size_t dst = (size_t)idx * 8;
    #pragma unroll
    for (int e = 0; e < 8; ++e) {
        float v = W[src + e];
        unsigned short h = bf16_rne(v);
        hi[dst + e] = (short)h;
        lo[dst + e] = (short)bf16_rne(v - bf16_to_f(h));
    }
}

// ---- initial h fp32 [r][k] -> A-frag layout [rt32][kt16][lane64][e8], hi+lo split
__global__ __launch_bounds__(256)
void cvt_hfrag(const float* __restrict__ Hsrc, short* __restrict__ hi, short* __restrict__ lo)
{
    int idx = blockIdx.x * 256 + threadIdx.x;   // 0..32767
    int l  = idx & 63;
    int kt = (idx >> 6) & 15;
    int rt = idx >> 10;
    int r = rt * 16 + (l & 15);
    int k = kt * 32 + (l >> 4) * 8;
    size_t src = (size_t)r * HH + k;
    size_t dst = (size_t)idx * 8;
    #pragma unroll
    for (int e = 0; e < 8; ++e) {
        float v = Hsrc[src + e];
        unsigned short h = bf16_rne(v);
        hi[dst + e] = (short)h;
        lo[dst + e] = (short)bf16_rne(v - bf16_to_f(h));
    }
}

__global__ void zero_sync(unsigned* s) { s[threadIdx.x] = 0u; }   // 512 threads

// ---- grid barrier: tree arrival (8 groups x 32), monotonic counters, acquire-LOAD polling.
// sync layout: [g*32] group counters (g=0..7, 128B apart), [256] root, [320] generation.
__device__ __forceinline__ void grid_barrier(unsigned* sync, int p, int bid)
{
    __syncthreads();
    if (threadIdx.x == 0) {
        __threadfence();   // release: write back dirty L2 (h-frags) to coherence point
        const int g = bid & 7;
        unsigned a = __hip_atomic_fetch_add(&sync[g * 32], 1u,
                        __ATOMIC_ACQ_REL, __HIP_MEMORY_SCOPE_AGENT);
        if (a == (unsigned)((NBLK / 8) * (p + 1) - 1)) {
            unsigned r = __hip_atomic_fetch_add(&sync[256], 1u,
                            __ATOMIC_ACQ_REL, __HIP_MEMORY_SCOPE_AGENT);
            if (r == (unsigned)(8 * (p + 1) - 1)) {
                __hip_atomic_store(&sync[320], (unsigned)(p + 1),
                                   __ATOMIC_RELEASE, __HIP_MEMORY_SCOPE_AGENT);
            }
        }
        while (__hip_atomic_load(&sync[320], __ATOMIC_ACQUIRE,
                                 __HIP_MEMORY_SCOPE_AGENT) < (unsigned)(p + 1)) {
            __builtin_amdgcn_s_sleep(1);
        }
        __threadfence();   // acquire: invalidate local L2 so fresh h-frags are fetched
    }
    __syncthreads();
}

// K-split(8) LDS tree reduction + fused LSTM cell epilogue (c-state in registers).
// acc tiles: acc[rt][g], C-frag: row_local = rt*16 + (l>>4)*4 + q, col = l&15
template<int LAYER>
__device__ __forceinline__ void reduce_epilogue(
    f32x4 (&acc)[4][4], float (*quad)[4096],
    int kh, int l, int tid, int jt, int rblk, int p,
    const float* __restrict__ bih, const float* __restrict__ bhh,
    const float* __restrict__ cinit,   // non-null only on this layer's first phase
    f32x4& cstate,
    short* __restrict__ hfh, short* __restrict__ hfl,
    float* __restrict__ Hf,
    const float* __restrict__ Wih0, const float* __restrict__ x)
{
    // round A: kh 4..7 -> quad[kh-4]
    if (kh >= 4) {
        #pragma unroll
        for (int rt = 0; rt < 4; ++rt)
            #pragma unroll
            for (int g = 0; g < 4; ++g)
                #pragma unroll
                for (int q = 0; q < 4; ++q)
                    quad[kh - 4][(g*64 + rt*16 + (l>>4)*4 + q)*16 + (l&15)] = acc[rt][g][q];
    }
    __syncthreads();
    if (kh < 4) {
        #pragma unroll
        for (int rt = 0; rt < 4; ++rt)
            #pragma unroll
            for (int g = 0; g < 4; ++g)
                #pragma unroll
                for (int q = 0; q < 4; ++q)
                    acc[rt][g][q] += quad[kh][(g*64 + rt*16 + (l>>4)*4 + q)*16 + (l&15)];
    }
    __syncthreads();
    if (kh == 2 || kh == 3) {
        #pragma unroll
        for (int rt = 0; rt < 4; ++rt)
            #pragma unroll
            for (int g = 0; g < 4; ++g)
                #pragma unroll
                for (int q = 0; q < 4; ++q)
                    quad[kh][(g*64 + rt*16 + (l>>4)*4 + q)*16 + (l&15)] = acc[rt][g][q];
    }
    __syncthreads();
    if (kh == 0 || kh == 1) {
        #pragma unroll
        for (int rt = 0; rt < 4; ++rt)
            #pragma unroll
            for (int g = 0; g < 4; ++g)
                #pragma unroll
                for (int q = 0; q < 4; ++q)
                    acc[rt][g][q] += quad[kh + 2][(g*64 + rt*16 + (l>>4)*4 + q)*16 + (l&15)];
        if (kh == 1) {
            #pragma unroll
            for (int rt = 0; rt < 4; ++rt)
                #pragma unroll
                for (int g = 0; g < 4; ++g)
                    #pragma unroll
                    for (int q = 0; q < 4; ++q)
                        quad[1][(g*64 + rt*16 + (l>>4)*4 + q)*16 + (l&15)] = acc[rt][g][q];
        }
    }
    __syncthreads();
    if (kh == 0) {
        #pragma unroll
        for (int rt = 0; rt < 4; ++rt)
            #pragma unroll
            for (int g = 0; g < 4; ++g) {
                #pragma unroll
                for (int q = 0; q < 4; ++q) {
                    acc[rt][g][q] += quad[1][(g*64 + rt*16 + (l>>4)*4 + q)*16 + (l&15)];
                    quad[0][(g*64 + rt*16 + (l>>4)*4 + q)*16 + (l&15)] = acc[rt][g][q];
                }
            }
    }
    __syncthreads();

    // epilogue: 256 threads, each (row, j-quad); c-state lives in this thread's registers
    if (tid < 256) {
        const int rl = tid >> 2;
        const int jl = (tid & 3) * 4;
        const int r  = rblk * 64 + rl;
        const int j  = jt * 16 + jl;
        f32x4 gv[4];
        #pragma unroll
        for (int g = 0; g < 4; ++g) {
            gv[g] = *(const f32x4*)&quad[0][(g*64 + rl)*16 + jl];
            f32x4 b1 = *(const f32x4*)&bih[g*HH + j];
            f32x4 b2 = *(const f32x4*)&bhh[g*HH + j];
            #pragma unroll
            for (int q = 0; q < 4; ++q) gv[g][q] += b1[q] + b2[q];
        }
        if (LAYER == 0) {
            const float x0 = x[(size_t)p * BB * XD0 + r * XD0 + 0];
            const float x1 = x[(size_t)p * BB * XD0 + r * XD0 + 1];
            const float x2 = x[(size_t)p * BB * XD0 + r * XD0 + 2];
            #pragma unroll
            for (int g = 0; g < 4; ++g)
                #pragma unroll
                for (int e = 0; e < 4; ++e) {
                    const float* wr_ = &Wih0[(size_t)(g*HH + j + e) * XD0];
                    gv[g][e] += x0 * wr_[0] + x1 * wr_[1] + x2 * wr_[2];
                }
        }
        f32x4 cv = cstate;
        if (cinit != nullptr) cv = *(const f32x4*)&cinit[(size_t)r * HH + j];
        float hn[4];
        #pragma unroll
        for (int e = 0; e < 4; ++e) {
            float I = sigmoid_(gv[0][e]);
            float F = sigmoid_(gv[1][e]);
            float G = tanh_(gv[2][e]);
            float O = sigmoid_(gv[3][e]);
            float cn = F * cv[e] + I * G;
            cv[e] = cn;
            hn[e] = O * tanh_(cn);
        }
        cstate = cv;
        // h -> A-frag layout (4 bf16 hi + 4 lo, 8B each)
        const int ktj   = j >> 5;
        const int lanew = (r & 15) | (((j & 31) >> 3) << 4);
        const int e0    = j & 7;      // 0 or 4
        const int rtg   = r >> 4;
        size_t hoff = ((((size_t)rtg)*16 + ktj)*64 + lanew)*8 + e0;
        short4v hhi, hlo;
        #pragma unroll
        for (int e = 0; e < 4; ++e) {
            unsigned short hb = bf16_rne(hn[e]);
            hhi[e] = (short)hb;
            hlo[e] = (short)bf16_rne(hn[e] - bf16_to_f(hb));
        }
        *(short4v*)&hfh[hoff] = hhi;
        *(short4v*)&hfl[hoff] = hlo;
        if (Hf != nullptr) {
            f32x4 hv;
            #pragma unroll
            for (int e = 0; e < 4; ++e) hv[e] = hn[e];
            *(f32x4*)&Hf[(size_t)r * HH + j] = hv;
        }
    }
    __syncthreads();   // protect quad reuse
}

__global__ __launch_bounds__(512, 2)
void lstm_persist(
    const short* __restrict__ W0h, const short* __restrict__ W0l,
    const short* __restrict__ W1h, const short* __restrict__ W1l,
    const short* __restrict__ WIh, const short* __restrict__ WIl,
    const float* __restrict__ Wih0, const float* __restrict__ x,
    const float* __restrict__ bih0, const float* __restrict__ bhh0,
    const float* __restrict__ bih1, const float* __restrict__ bhh1,
    const float* __restrict__ c0in,
    short* __restrict__ h0fh0, short* __restrict__ h0fl0,
    short* __restrict__ h0fh1, short* __restrict__ h0fl1,
    short* __restrict__ h1fh0, short* __restrict__ h1fl0,
    short* __restrict__ h1fh1, short* __restrict__ h1fl1,
    float* __restrict__ H0f, float* __restrict__ H1f,
    unsigned* __restrict__ sync)
{
    __shared__ float quad[4][4096];   // 64 KB

    const int tid  = threadIdx.x;
    const int kh   = tid >> 6;
    const int l    = tid & 63;
    const int bid  = blockIdx.x;
    const int jt   = bid & 31;        // XCD = bid%8 -> same-j weights per XCD
    const int rblk = bid >> 5;

    // persistent B_hi fragments (96 VGPRs)
    short8 b0h[2][4];
    short8 b1h[4][4];
    #pragma unroll
    for (int kk = 0; kk < 2; ++kk)
        #pragma unroll
        for (int g = 0; g < 4; ++g)
            b0h[kk][g] = *(const short8*)&W0h[((((size_t)jt*4 + g)*16 + (kh + kk*8))*64 + l)*8];
    #pragma unroll
    for (int kk = 0; kk < 4; ++kk)
        #pragma unroll
        for (int g = 0; g < 4; ++g) {
            const short* Wh = (kk < 2) ? W1h : WIh;
            const int kt = kh + (kk & 1) * 8;
            b1h[kk][g] = *(const short8*)&Wh[((((size_t)jt*4 + g)*16 + kt)*64 + l)*8];
        }

    // per-thread recurrent c-state (valid for tid<256)
    f32x4 c0reg, c1reg;
    #pragma unroll
    for (int e = 0; e < 4; ++e) { c0reg[e] = 0.0f; c1reg[e] = 0.0f; }

    for (int p = 0; p <= SS; ++p) {
        const int par = p & 1;
        // ---------------- layer 0, step p ----------------
        if (p < SS) {
            const short* Ah = par ? h0fh1 : h0fh0;
            const short* Al = par ? h0fl1 : h0fl0;
            f32x4 acc[4][4];
            #pragma unroll
            for (int rt = 0; rt < 4; ++rt)
                #pragma unroll
                for (int g = 0; g < 4; ++g)
                    #pragma unroll
                    for (int q = 0; q < 4; ++q) acc[rt][g][q] = 0.0f;
            #pragma unroll
            for (int kk = 0; kk < 2; ++kk) {
                const int kt = kh + kk * 8;
                short8 bl[4];
                #pragma unroll
                for (int g = 0; g < 4; ++g)
                    bl[g] = *(const short8*)&W0l[((((size_t)jt*4 + g)*16 + kt)*64 + l)*8];
                #pragma unroll
                for (int rt = 0; rt < 4; ++rt) {
                    const size_t ab = ((((size_t)(rblk*4 + rt))*16 + kt)*64 + l)*8;
                    short8 ah = *(const short8*)&Ah[ab];
                    short8 al = *(const short8*)&Al[ab];
                    #pragma unroll
                    for (int g = 0; g < 4; ++g) {
                        acc[rt][g] = __builtin_amdgcn_mfma_f32_16x16x32_bf16(ah, b0h[kk][g], acc[rt][g], 0,0,0);
                        acc[rt][g] = __builtin_amdgcn_mfma_f32_16x16x32_bf16(ah, bl[g],      acc[rt][g], 0,0,0);
                        acc[rt][g] = __builtin_amdgcn_mfma_f32_16x16x32_bf16(al, b0h[kk][g], acc[rt][g], 0,0,0);
                    }
                }
            }
            reduce_epilogue<0>(acc, quad, kh, l, tid, jt, rblk, p,
                               bih0, bhh0,
                               (p == 0) ? c0in : nullptr, c0reg,
                               par ? h0fh0 : h0fh1, par ? h0fl0 : h0fl1,
                               (p == SS - 1) ? H0f : nullptr, Wih0, x);
        }
        // ---------------- layer 1, step p-1 ----------------
        if (p >= 1) {
            const short* A1h = par ? h1fh1 : h1fh0;
            const short* A1l = par ? h1fl1 : h1fl0;
            const short* Y0h = par ? h0fh1 : h0fh0;
            const short* Y0l = par ? h0fl1 : h0fl0;
            f32x4 acc[4][4];
            #pragma unroll
            for (int rt = 0; rt < 4; ++rt)
                #pragma unroll
                for (int g = 0; g < 4; ++g)
                    #pragma unroll
                    for (int q = 0; q < 4; ++q) acc[rt][g][q] = 0.0f;
            #pragma unroll
            for (int kk = 0; kk < 4; ++kk) {
                const int kt = kh + (kk & 1) * 8;
                const short* Ah = (kk < 2) ? A1h : Y0h;
                const short* Al = (kk < 2) ? A1l : Y0l;
                const short* Wl = (kk < 2) ? W1l : WIl;
                short8 bl[4];
                #pragma unroll
                for (int g = 0; g < 4; ++g)
                    bl[g] = *(const short8*)&Wl[((((size_t)jt*4 + g)*16 + kt)*64 + l)*8];
                #pragma unroll
                for (int rt = 0; rt < 4; ++rt) {
                    const size_t ab = ((((size_t)(rblk*4 + rt))*16 + kt)*64 + l)*8;
                    short8 ah = *(const short8*)&Ah[ab];
                    short8 al = *(const short8*)&Al[ab];
                    #pragma unroll
                    for (int g = 0; g < 4; ++g) {
                        acc[rt][g] = __builtin_amdgcn_mfma_f32_16x16x32_bf16(ah, b1h[kk][g], acc[rt][g], 0,0,0);
                        acc[rt][g] = __builtin_amdgcn_mfma_f32_16x16x32_bf16(ah, bl[g],      acc[rt][g], 0,0,0);
                        acc[rt][g] = __builtin_amdgcn_mfma_f32_16x16x32_bf16(al, b1h[kk][g], acc[rt][g], 0,0,0);
                    }
                }
            }
            reduce_epilogue<1>(acc, quad, kh, l, tid, jt, rblk, p,
                               bih1, bhh1,
                               (p == 1) ? (c0in + (size_t)BB*HH) : nullptr, c1reg,
                               par ? h1fh0 : h1fh1, par ? h1fl0 : h1fl1,
                               (p == SS) ? H1f : nullptr, Wih0, x);
        }
        grid_barrier(sync, p, bid);
    }
}

// td[b][s] = btd[s] + cat(h0T,h1T)[b][:] . Wtd[s][:]  (validated R1/R2)
__global__ __launch_bounds__(256)
void td_kernel(const float* __restrict__ h0T, const float* __restrict__ h1T,
               const float* __restrict__ Wtd, const float* __restrict__ btd,
               float* __restrict__ td)
{
    __shared__ float a_lds[TM][TK + 1];
    __shared__ float b_lds[TN][TK + 1];
    const int t = threadIdx.x;
    const int nl = t & 31;
    const int mq = t >> 5;
    const int n0 = blockIdx.x * TN;
    const int m0 = blockIdx.y * TM;
    float acc[4] = {0.f, 0.f, 0.f, 0.f};

    for (int k0 = 0; k0 < 2 * HH; k0 += TK) {
        const float* src = (k0 < HH) ? h0T : h1T;
        int kb = k0 & (HH - 1);
        #pragma unroll
        for (int i = 0; i < (TM * TK) / 256; ++i) {
            int idx = t + i * 256;
            int r = idx >> 5, kk = idx & 31;
            a_lds[r][kk] = src[(size_t)(m0 + r) * HH + kb + kk];
        }
        #pragma unroll
        for (int i = 0; i < (TN * TK) / 256; ++i) {
            int idx = t + i * 256;
            int jn = idx >> 5, kk = idx & 31;
            b_lds[jn][kk] = Wtd[(size_t)(n0 + jn) * (2 * HH) + k0 + kk];
        }
        __syncthreads();
        #pragma unroll
        for (int kk = 0; kk < TK; ++kk) {
            float bv = b_lds[nl][kk];
            #pragma unroll
            for (int rr = 0; rr < 4; ++rr)
                acc[rr] = fmaf(a_lds[mq * 4 + rr][kk], bv, acc[rr]);
        }
        __syncthreads();
    }
    #pragma unroll
    for (int rr = 0; rr < 4; ++rr)
        td[(size_t)(m0 + mq * 4 + rr) * TDN + n0 + nl] = acc[rr] + btd[n0 + nl];
}

__global__ __launch_bounds__(256)
void fc_kernel(const float* __restrict__ td,
               const float* __restrict__ Wfc1, const float* __restrict__ bfc1,
               const float* __restrict__ Wfc2, const float* __restrict__ bfc2,
               float* __restrict__ out)
{
    __shared__ float td_lds[32][TDN];
    __shared__ float f1_lds[32][FC1N];
    const int t = threadIdx.x;
    const int r0 = blockIdx.x * 32;

    #pragma unroll
    for (int i = 0; i < (32 * TDN) / 256; ++i) {
        int idx = t + i * 256;
        int r = idx >> 8, k = idx & 255;
        td_lds[r][k] = td[(size_t)(r0 + r) * TDN + k];
    }
    __syncthreads();

    for (int idx = t; idx < 32 * FC1N; idx += 256) {
        int r = idx / FC1N, o = idx % FC1N;
        float s = bfc1[o];
        for (int k = 0; k < TDN; ++k) s = fmaf(td_lds[r][k], Wfc1[o * TDN + k], s);
        f1_lds[r][o] = fmaxf(s, 0.0f);
    }
    __syncthreads();

    for (int idx = t; idx < 32 * OUTN; idx += 256) {
        int r = idx / OUTN, o = idx % OUTN;
        float s = bfc2[o];
        for (int k = 0; k < FC1N; ++k) s = fmaf(f1_lds[r][k], Wfc2[o * FC1N + k], s);
        out[(size_t)(r0 + r) * OUTN + o] = s;
    }
}

extern "C" void kernel_launch(void* const* d_in, const int* in_sizes, int n_in,
                              void* d_out, int out_size, void* d_ws, size_t ws_size,
                              hipStream_t stream)
{
    const float* x    = (const float*)d_in[0];
    const float* h0   = (const float*)d_in[1];
    const float* c0   = (const float*)d_in[2];
    const float* Wih0 = (const float*)d_in[3];
    const float* Whh0 = (const float*)d_in[4];
    const float* bih0 = (const float*)d_in[5];
    const float* bhh0 = (const float*)d_in[6];
    const float* Wih1 = (const float*)d_in[7];
    const float* Whh1 = (const float*)d_in[8];
    const float* bih1 = (const float*)d_in[9];
    const float* bhh1 = (const float*)d_in[10];
    const float* Wtd  = (const float*)d_in[11];
    const float* btd  = (const float*)d_in[12];
    const float* Wfc1 = (const float*)d_in[13];
    const float* bfc1 = (const float*)d_in[14];
    const float* Wfc2 = (const float*)d_in[15];
    const float* bfc2 = (const float*)d_in[16];
    float* out = (float*)d_out;

    const size_t WSZ = (size_t)4 * HH * HH;      // 1M elems
    const size_t HFR = (size_t)32 * 16 * 64 * 8; // 262144 elems
    const size_t HSZ = (size_t)BB * HH;

    char* pp = (char*)d_ws;
    short* W0h = (short*)pp; pp += WSZ * 2;
    short* W0l = (short*)pp; pp += WSZ * 2;
    short* W1h = (short*)pp; pp += WSZ * 2;
    short* W1l = (short*)pp; pp += WSZ * 2;
    short* WIh = (short*)pp; pp += WSZ * 2;
    short* WIl = (short*)pp; pp += WSZ * 2;
    short* h0fh0 = (short*)pp; pp += HFR * 2;
    short* h0fl0 = (short*)pp; pp += HFR * 2;
    short* h0fh1 = (short*)pp; pp += HFR * 2;
    short* h0fl1 = (short*)pp; pp += HFR * 2;
    short* h1fh0 = (short*)pp; pp += HFR * 2;
    short* h1fl0 = (short*)pp; pp += HFR * 2;
    short* h1fh1 = (short*)pp; pp += HFR * 2;
    short* h1fl1 = (short*)pp; pp += HFR * 2;
    float* H0f = (float*)pp; pp += HSZ * 4;
    float* H1f = (float*)pp; pp += HSZ * 4;
    float* TD  = (float*)pp; pp += (size_t)BB * TDN * 4;
    unsigned* sync = (unsigned*)pp; pp += 512 * 4;

    // one-time (per call) weight/state conversion to fragment layouts
    cvt_wfrag<<<dim3(512), dim3(256), 0, stream>>>(Whh0, W0h, W0l);
    cvt_wfrag<<<dim3(512), dim3(256), 0, stream>>>(Whh1, W1h, W1l);
    cvt_wfrag<<<dim3(512), dim3(256), 0, stream>>>(Wih1, WIh, WIl);
    cvt_hfrag<<<dim3(128), dim3(256), 0, stream>>>(h0,        h0fh0, h0fl0);   // layer0 init -> parity 0
    cvt_hfrag<<<dim3(128), dim3(256), 0, stream>>>(h0 + HSZ,  h1fh1, h1fl1);   // layer1 init -> parity 1
    zero_sync<<<dim3(1), dim3(512), 0, stream>>>(sync);

    lstm_persist<<<dim3(NBLK), dim3(512), 0, stream>>>(
        W0h, W0l, W1h, W1l, WIh, WIl,
        Wih0, x, bih0, bhh0, bih1, bhh1, c0,
        h0fh0, h0fl0, h0fh1, h0fl1,
        h1fh0, h1fl0, h1fh1, h1fl1,
        H0f, H1f, sync);

    const dim3 gtd(TDN / TN, BB / TM);
    td_kernel<<<gtd, dim3(256), 0, stream>>>(H0f, H1f, Wtd, btd, TD);
    fc_kernel<<<dim3(BB / 32), dim3(256), 0, stream>>>(TD, Wfc1, bfc1, Wfc2, bfc2, out);

    (void)in_sizes; (void)n_in; (void)out_size; (void)ws_size;
}

// Round 5
// 11983.138 us; speedup vs baseline: 1.5512x; 1.5512x over previous
//
#include <hip/hip_runtime.h>
#include <math.h>

#define BB 512
#define HH 512
#define SS 256
#define XD0 3
#define TDN 256
#define FC1N 20
#define OUTN 2
#define TM 32
#define TN 32
#define TK 32
#define NBLK 256   // persistent grid size (== #CUs; 1 block/CU guaranteed co-resident)

typedef __attribute__((ext_vector_type(8))) short short8;
typedef __attribute__((ext_vector_type(4))) short short4v;
typedef __attribute__((ext_vector_type(4))) float f32x4;

__device__ __forceinline__ unsigned short bf16_rne(float f) {
    unsigned u = __float_as_uint(f);
    u += 0x7FFFu + ((u >> 16) & 1u);
    return (unsigned short)(u >> 16);
}
__device__ __forceinline__ float bf16_to_f(unsigned short h) {
    return __uint_as_float(((unsigned)h) << 16);
}
__device__ __forceinline__ float sigmoid_(float x) { return 1.0f / (1.0f + __expf(-x)); }
__device__ __forceinline__ float tanh_(float x) {
    float e = __expf(2.0f * x);
    return 1.0f - 2.0f / (e + 1.0f);
}

// ---- weights fp32 [4H][H] -> MFMA B-frag layout [jt32][g4][kt16][lane64][e8], hi+lo split
__global__ __launch_bounds__(256)
void cvt_wfrag(const float* __restrict__ W, short* __restrict__ hi, short* __restrict__ lo)
{
    int idx = blockIdx.x * 256 + threadIdx.x;   // 0..131071
    int l   = idx & 63;
    int kt  = (idx >> 6) & 15;
    int g   = (idx >> 10) & 3;
    int jt  = idx >> 12;
    int row = g * HH + jt * 16 + (l & 15);
    int col = kt * 32 + (l >> 4) * 8;
    size_t src = (size_t)row * HH + col;
    size_t dst = (size_t)idx * 8;
    #pragma unroll
    for (int e = 0; e < 8; ++e) {
        float v = W[src + e];
        unsigned short h = bf16_rne(v);
        hi[dst + e] = (short)h;
        lo[dst + e] = (short)bf16_rne(v - bf16_to_f(h));
    }
}

// ---- initial h fp32 [r][k] -> A-frag layout [rt32][kt16][lane64][e8], hi+lo split
__global__ __launch_bounds__(256)
void cvt_hfrag(const float* __restrict__ Hsrc, short* __restrict__ hi, short* __restrict__ lo)
{
    int idx = blockIdx.x * 256 + threadIdx.x;   // 0..32767
    int l  = idx & 63;
    int kt = (idx >> 6) & 15;
    int rt = idx >> 10;
    int r = rt * 16 + (l & 15);
    int k = kt * 32 + (l >> 4) * 8;
    size_t src = (size_t)r * HH + k;
    size_t dst = (size_t)idx * 8;
    #pragma unroll
    for (int e = 0; e < 8; ++e) {
        float v = Hsrc[src + e];
        unsigned short h = bf16_rne(v);
        hi[dst + e] = (short)h;
        lo[dst + e] = (short)bf16_rne(v - bf16_to_f(h));
    }
}

__global__ void zero_sync(unsigned* s) { s[threadIdx.x] = 0u; }   // 512 threads

// ---- grid barrier: tree arrival (8 groups x 32, one line each), monotonic counters.
// CRITICAL: poll with RELAXED agent loads (no buffer_inv per iteration!), then ONE
// acquire fence after exit. R4's acquire-load-in-loop invalidated the XCD L2
// continuously and collapsed chip BW to ~650 GB/s.
__device__ __forceinline__ void grid_barrier(unsigned* sync, int p, int bid)
{
    __syncthreads();
    if (threadIdx.x == 0) {
        __threadfence();   // release: write back dirty h-frags toward coherence point
        const int g = bid & 7;
        unsigned a = __hip_atomic_fetch_add(&sync[g * 32], 1u,
                        __ATOMIC_RELAXED, __HIP_MEMORY_SCOPE_AGENT);
        if (a == (unsigned)((NBLK / 8) * (p + 1) - 1)) {
            unsigned r = __hip_atomic_fetch_add(&sync[256], 1u,
                            __ATOMIC_RELAXED, __HIP_MEMORY_SCOPE_AGENT);
            if (r == (unsigned)(8 * (p + 1) - 1)) {
                __hip_atomic_store(&sync[320], (unsigned)(p + 1),
                                   __ATOMIC_RELAXED, __HIP_MEMORY_SCOPE_AGENT);
            }
        }
        while (__hip_atomic_load(&sync[320], __ATOMIC_RELAXED,
                                 __HIP_MEMORY_SCOPE_AGENT) < (unsigned)(p + 1)) {
            __builtin_amdgcn_s_sleep(2);
        }
        __threadfence();   // acquire: single invalidate so fresh h-frags are fetched
    }
    __syncthreads();
}

// K-split(8) LDS tree reduction + fused LSTM cell epilogue (c-state in registers).
// acc tiles: acc[rt][g], C-frag: row_local = rt*16 + (l>>4)*4 + q, col = l&15
template<int LAYER>
__device__ __forceinline__ void reduce_epilogue(
    f32x4 (&acc)[4][4], float (*quad)[4096],
    int kh, int l, int tid, int jt, int rblk, int p,
    const float* __restrict__ sbias,   // LDS: [g*16 + jl] = bih+bhh for this block's j
    const float* __restrict__ swin,    // LDS: [(g*16+jl)*3 + d] Wih0 slice (layer0)
    const float* __restrict__ cinit,   // non-null only on this layer's first phase
    f32x4& cstate,
    short* __restrict__ hfh, short* __restrict__ hfl,
    float* __restrict__ Hf,
    const float* __restrict__ x)
{
    // round A: kh 4..7 -> quad[kh-4]
    if (kh >= 4) {
        #pragma unroll
        for (int rt = 0; rt < 4; ++rt)
            #pragma unroll
            for (int g = 0; g < 4; ++g)
                #pragma unroll
                for (int q = 0; q < 4; ++q)
                    quad[kh - 4][(g*64 + rt*16 + (l>>4)*4 + q)*16 + (l&15)] = acc[rt][g][q];
    }
    __syncthreads();
    if (kh < 4) {
        #pragma unroll
        for (int rt = 0; rt < 4; ++rt)
            #pragma unroll
            for (int g = 0; g < 4; ++g)
                #pragma unroll
                for (int q = 0; q < 4; ++q)
                    acc[rt][g][q] += quad[kh][(g*64 + rt*16 + (l>>4)*4 + q)*16 + (l&15)];
    }
    __syncthreads();
    if (kh == 2 || kh == 3) {
        #pragma unroll
        for (int rt = 0; rt < 4; ++rt)
            #pragma unroll
            for (int g = 0; g < 4; ++g)
                #pragma unroll
                for (int q = 0; q < 4; ++q)
                    quad[kh][(g*64 + rt*16 + (l>>4)*4 + q)*16 + (l&15)] = acc[rt][g][q];
    }
    __syncthreads();
    if (kh == 0 || kh == 1) {
        #pragma unroll
        for (int rt = 0; rt < 4; ++rt)
            #pragma unroll
            for (int g = 0; g < 4; ++g)
                #pragma unroll
                for (int q = 0; q < 4; ++q)
                    acc[rt][g][q] += quad[kh + 2][(g*64 + rt*16 + (l>>4)*4 + q)*16 + (l&15)];
        if (kh == 1) {
            #pragma unroll
            for (int rt = 0; rt < 4; ++rt)
                #pragma unroll
                for (int g = 0; g < 4; ++g)
                    #pragma unroll
                    for (int q = 0; q < 4; ++q)
                        quad[1][(g*64 + rt*16 + (l>>4)*4 + q)*16 + (l&15)] = acc[rt][g][q];
        }
    }
    __syncthreads();
    if (kh == 0) {
        #pragma unroll
        for (int rt = 0; rt < 4; ++rt)
            #pragma unroll
            for (int g = 0; g < 4; ++g) {
                #pragma unroll
                for (int q = 0; q < 4; ++q) {
                    acc[rt][g][q] += quad[1][(g*64 + rt*16 + (l>>4)*4 + q)*16 + (l&15)];
                    quad[0][(g*64 + rt*16 + (l>>4)*4 + q)*16 + (l&15)] = acc[rt][g][q];
                }
            }
    }
    __syncthreads();

    // epilogue: 256 threads, each (row, j-quad); c-state lives in this thread's registers
    if (tid < 256) {
        const int rl = tid >> 2;
        const int jl = (tid & 3) * 4;
        const int r  = rblk * 64 + rl;
        const int j  = jt * 16 + jl;
        f32x4 gv[4];
        #pragma unroll
        for (int g = 0; g < 4; ++g) {
            gv[g] = *(const f32x4*)&quad[0][(g*64 + rl)*16 + jl];
            f32x4 bv = *(const f32x4*)&sbias[g*16 + jl];
            #pragma unroll
            for (int q = 0; q < 4; ++q) gv[g][q] += bv[q];
        }
        if (LAYER == 0) {
            const float x0 = x[(size_t)p * BB * XD0 + r * XD0 + 0];
            const float x1 = x[(size_t)p * BB * XD0 + r * XD0 + 1];
            const float x2 = x[(size_t)p * BB * XD0 + r * XD0 + 2];
            #pragma unroll
            for (int g = 0; g < 4; ++g)
                #pragma unroll
                for (int e = 0; e < 4; ++e) {
                    const float* wr_ = &swin[(g*16 + jl + e) * 3];
                    gv[g][e] += x0 * wr_[0] + x1 * wr_[1] + x2 * wr_[2];
                }
        }
        f32x4 cv = cstate;
        if (cinit != nullptr) cv = *(const f32x4*)&cinit[(size_t)r * HH + j];
        float hn[4];
        #pragma unroll
        for (int e = 0; e < 4; ++e) {
            float I = sigmoid_(gv[0][e]);
            float F = sigmoid_(gv[1][e]);
            float G = tanh_(gv[2][e]);
            float O = sigmoid_(gv[3][e]);
            float cn = F * cv[e] + I * G;
            cv[e] = cn;
            hn[e] = O * tanh_(cn);
        }
        cstate = cv;
        // h -> A-frag layout (4 bf16 hi + 4 lo, 8B each)
        const int ktj   = j >> 5;
        const int lanew = (r & 15) | (((j & 31) >> 3) << 4);
        const int e0    = j & 7;      // 0 or 4
        const int rtg   = r >> 4;
        size_t hoff = ((((size_t)rtg)*16 + ktj)*64 + lanew)*8 + e0;
        short4v hhi, hlo;
        #pragma unroll
        for (int e = 0; e < 4; ++e) {
            unsigned short hb = bf16_rne(hn[e]);
            hhi[e] = (short)hb;
            hlo[e] = (short)bf16_rne(hn[e] - bf16_to_f(hb));
        }
        *(short4v*)&hfh[hoff] = hhi;
        *(short4v*)&hfl[hoff] = hlo;
        if (Hf != nullptr) {
            f32x4 hv;
            #pragma unroll
            for (int e = 0; e < 4; ++e) hv[e] = hn[e];
            *(f32x4*)&Hf[(size_t)r * HH + j] = hv;
        }
    }
    __syncthreads();   // protect quad reuse
}

__global__ __launch_bounds__(512, 2)
void lstm_persist(
    const short* __restrict__ W0h, const short* __restrict__ W0l,
    const short* __restrict__ W1h, const short* __restrict__ W1l,
    const short* __restrict__ WIh, const short* __restrict__ WIl,
    const float* __restrict__ Wih0, const float* __restrict__ x,
    const float* __restrict__ bih0, const float* __restrict__ bhh0,
    const float* __restrict__ bih1, const float* __restrict__ bhh1,
    const float* __restrict__ c0in,
    short* __restrict__ h0fh0, short* __restrict__ h0fl0,
    short* __restrict__ h0fh1, short* __restrict__ h0fl1,
    short* __restrict__ h1fh0, short* __restrict__ h1fl0,
    short* __restrict__ h1fh1, short* __restrict__ h1fl1,
    float* __restrict__ H0f, float* __restrict__ H1f,
    unsigned* __restrict__ sync)
{
    __shared__ float quad[4][4096];            // 64 KB
    __shared__ __align__(16) float sb[2][64];  // per-block bias sums (bih+bhh), both layers
    __shared__ float swin[192];                // per-block Wih0 slice [g*16+jl][3]

    const int tid  = threadIdx.x;
    const int kh   = tid >> 6;
    const int l    = tid & 63;
    const int bid  = blockIdx.x;
    const int jt   = bid & 31;        // XCD = bid%8 -> same-j weights per XCD
    const int rblk = bid >> 5;

    // one-time LDS preload of bias sums + Wih0 slice (were per-phase cold-L2 reads)
    if (tid < 128) {
        const int L = tid >> 6;
        const int gj = tid & 63;
        const int g = gj >> 4, jl = gj & 15;
        const int j = jt * 16 + jl;
        const float* bi = L ? bih1 : bih0;
        const float* bh = L ? bhh1 : bhh0;
        sb[L][gj] = bi[g * HH + j] + bh[g * HH + j];
    } else if (tid < 320) {
        const int q = tid - 128;            // 0..191
        const int gj = q / 3, d = q - gj * 3;
        const int g = gj >> 4, jl = gj & 15;
        const int j = jt * 16 + jl;
        swin[q] = Wih0[(size_t)(g * HH + j) * XD0 + d];
    }

    // persistent B_hi fragments (96 VGPRs)
    short8 b0h[2][4];
    short8 b1h[4][4];
    #pragma unroll
    for (int kk = 0; kk < 2; ++kk)
        #pragma unroll
        for (int g = 0; g < 4; ++g)
            b0h[kk][g] = *(const short8*)&W0h[((((size_t)jt*4 + g)*16 + (kh + kk*8))*64 + l)*8];
    #pragma unroll
    for (int kk = 0; kk < 4; ++kk)
        #pragma unroll
        for (int g = 0; g < 4; ++g) {
            const short* Wh = (kk < 2) ? W1h : WIh;
            const int kt = kh + (kk & 1) * 8;
            b1h[kk][g] = *(const short8*)&Wh[((((size_t)jt*4 + g)*16 + kt)*64 + l)*8];
        }

    // per-thread recurrent c-state (valid for tid<256)
    f32x4 c0reg, c1reg;
    #pragma unroll
    for (int e = 0; e < 4; ++e) { c0reg[e] = 0.0f; c1reg[e] = 0.0f; }

    __syncthreads();   // LDS preload visible

    for (int p = 0; p <= SS; ++p) {
        const int par = p & 1;
        // ---------------- layer 0, step p ----------------
        if (p < SS) {
            const short* Ah = par ? h0fh1 : h0fh0;
            const short* Al = par ? h0fl1 : h0fl0;
            f32x4 acc[4][4];
            #pragma unroll
            for (int rt = 0; rt < 4; ++rt)
                #pragma unroll
                for (int g = 0; g < 4; ++g)
                    #pragma unroll
                    for (int q = 0; q < 4; ++q) acc[rt][g][q] = 0.0f;
            #pragma unroll
            for (int kk = 0; kk < 2; ++kk) {
                const int kt = kh + kk * 8;
                short8 bl[4];
                #pragma unroll
                for (int g = 0; g < 4; ++g)
                    bl[g] = *(const short8*)&W0l[((((size_t)jt*4 + g)*16 + kt)*64 + l)*8];
                #pragma unroll
                for (int rt = 0; rt < 4; ++rt) {
                    const size_t ab = ((((size_t)(rblk*4 + rt))*16 + kt)*64 + l)*8;
                    short8 ah = *(const short8*)&Ah[ab];
                    short8 al = *(const short8*)&Al[ab];
                    #pragma unroll
                    for (int g = 0; g < 4; ++g) {
                        acc[rt][g] = __builtin_amdgcn_mfma_f32_16x16x32_bf16(ah, b0h[kk][g], acc[rt][g], 0,0,0);
                        acc[rt][g] = __builtin_amdgcn_mfma_f32_16x16x32_bf16(ah, bl[g],      acc[rt][g], 0,0,0);
                        acc[rt][g] = __builtin_amdgcn_mfma_f32_16x16x32_bf16(al, b0h[kk][g], acc[rt][g], 0,0,0);
                    }
                }
            }
            reduce_epilogue<0>(acc, quad, kh, l, tid, jt, rblk, p,
                               sb[0], swin,
                               (p == 0) ? c0in : nullptr, c0reg,
                               par ? h0fh0 : h0fh1, par ? h0fl0 : h0fl1,
                               (p == SS - 1) ? H0f : nullptr, x);
        }
        // ---------------- layer 1, step p-1 ----------------
        if (p >= 1) {
            const short* A1h = par ? h1fh1 : h1fh0;
            const short* A1l = par ? h1fl1 : h1fl0;
            const short* Y0h = par ? h0fh1 : h0fh0;
            const short* Y0l = par ? h0fl1 : h0fl0;
            f32x4 acc[4][4];
            #pragma unroll
            for (int rt = 0; rt < 4; ++rt)
                #pragma unroll
                for (int g = 0; g < 4; ++g)
                    #pragma unroll
                    for (int q = 0; q < 4; ++q) acc[rt][g][q] = 0.0f;
            #pragma unroll
            for (int kk = 0; kk < 4; ++kk) {
                const int kt = kh + (kk & 1) * 8;
                const short* Ah = (kk < 2) ? A1h : Y0h;
                const short* Al = (kk < 2) ? A1l : Y0l;
                const short* Wl = (kk < 2) ? W1l : WIl;
                short8 bl[4];
                #pragma unroll
                for (int g = 0; g < 4; ++g)
                    bl[g] = *(const short8*)&Wl[((((size_t)jt*4 + g)*16 + kt)*64 + l)*8];
                #pragma unroll
                for (int rt = 0; rt < 4; ++rt) {
                    const size_t ab = ((((size_t)(rblk*4 + rt))*16 + kt)*64 + l)*8;
                    short8 ah = *(const short8*)&Ah[ab];
                    short8 al = *(const short8*)&Al[ab];
                    #pragma unroll
                    for (int g = 0; g < 4; ++g) {
                        acc[rt][g] = __builtin_amdgcn_mfma_f32_16x16x32_bf16(ah, b1h[kk][g], acc[rt][g], 0,0,0);
                        acc[rt][g] = __builtin_amdgcn_mfma_f32_16x16x32_bf16(ah, bl[g],      acc[rt][g], 0,0,0);
                        acc[rt][g] = __builtin_amdgcn_mfma_f32_16x16x32_bf16(al, b1h[kk][g], acc[rt][g], 0,0,0);
                    }
                }
            }
            reduce_epilogue<1>(acc, quad, kh, l, tid, jt, rblk, p,
                               sb[1], swin,
                               (p == 1) ? (c0in + (size_t)BB*HH) : nullptr, c1reg,
                               par ? h1fh0 : h1fh1, par ? h1fl0 : h1fl1,
                               (p == SS) ? H1f : nullptr, x);
        }
        grid_barrier(sync, p, bid);
    }
}

// td[b][s] = btd[s] + cat(h0T,h1T)[b][:] . Wtd[s][:]  (validated R1/R2)
__global__ __launch_bounds__(256)
void td_kernel(const float* __restrict__ h0T, const float* __restrict__ h1T,
               const float* __restrict__ Wtd, const float* __restrict__ btd,
               float* __restrict__ td)
{
    __shared__ float a_lds[TM][TK + 1];
    __shared__ float b_lds[TN][TK + 1];
    const int t = threadIdx.x;
    const int nl = t & 31;
    const int mq = t >> 5;
    const int n0 = blockIdx.x * TN;
    const int m0 = blockIdx.y * TM;
    float acc[4] = {0.f, 0.f, 0.f, 0.f};

    for (int k0 = 0; k0 < 2 * HH; k0 += TK) {
        const float* src = (k0 < HH) ? h0T : h1T;
        int kb = k0 & (HH - 1);
        #pragma unroll
        for (int i = 0; i < (TM * TK) / 256; ++i) {
            int idx = t + i * 256;
            int r = idx >> 5, kk = idx & 31;
            a_lds[r][kk] = src[(size_t)(m0 + r) * HH + kb + kk];
        }
        #pragma unroll
        for (int i = 0; i < (TN * TK) / 256; ++i) {
            int idx = t + i * 256;
            int jn = idx >> 5, kk = idx & 31;
            b_lds[jn][kk] = Wtd[(size_t)(n0 + jn) * (2 * HH) + k0 + kk];
        }
        __syncthreads();
        #pragma unroll
        for (int kk = 0; kk < TK; ++kk) {
            float bv = b_lds[nl][kk];
            #pragma unroll
            for (int rr = 0; rr < 4; ++rr)
                acc[rr] = fmaf(a_lds[mq * 4 + rr][kk], bv, acc[rr]);
        }
        __syncthreads();
    }
    #pragma unroll
    for (int rr = 0; rr < 4; ++rr)
        td[(size_t)(m0 + mq * 4 + rr) * TDN + n0 + nl] = acc[rr] + btd[n0 + nl];
}

__global__ __launch_bounds__(256)
void fc_kernel(const float* __restrict__ td,
               const float* __restrict__ Wfc1, const float* __restrict__ bfc1,
               const float* __restrict__ Wfc2, const float* __restrict__ bfc2,
               float* __restrict__ out)
{
    __shared__ float td_lds[32][TDN];
    __shared__ float f1_lds[32][FC1N];
    const int t = threadIdx.x;
    const int r0 = blockIdx.x * 32;

    #pragma unroll
    for (int i = 0; i < (32 * TDN) / 256; ++i) {
        int idx = t + i * 256;
        int r = idx >> 8, k = idx & 255;
        td_lds[r][k] = td[(size_t)(r0 + r) * TDN + k];
    }
    __syncthreads();

    for (int idx = t; idx < 32 * FC1N; idx += 256) {
        int r = idx / FC1N, o = idx % FC1N;
        float s = bfc1[o];
        for (int k = 0; k < TDN; ++k) s = fmaf(td_lds[r][k], Wfc1[o * TDN + k], s);
        f1_lds[r][o] = fmaxf(s, 0.0f);
    }
    __syncthreads();

    for (int idx = t; idx < 32 * OUTN; idx += 256) {
        int r = idx / OUTN, o = idx % OUTN;
        float s = bfc2[o];
        for (int k = 0; k < FC1N; ++k) s = fmaf(f1_lds[r][k], Wfc2[o * FC1N + k], s);
        out[(size_t)(r0 + r) * OUTN + o] = s;
    }
}

extern "C" void kernel_launch(void* const* d_in, const int* in_sizes, int n_in,
                              void* d_out, int out_size, void* d_ws, size_t ws_size,
                              hipStream_t stream)
{
    const float* x    = (const float*)d_in[0];
    const float* h0   = (const float*)d_in[1];
    const float* c0   = (const float*)d_in[2];
    const float* Wih0 = (const float*)d_in[3];
    const float* Whh0 = (const float*)d_in[4];
    const float* bih0 = (const float*)d_in[5];
    const float* bhh0 = (const float*)d_in[6];
    const float* Wih1 = (const float*)d_in[7];
    const float* Whh1 = (const float*)d_in[8];
    const float* bih1 = (const float*)d_in[9];
    const float* bhh1 = (const float*)d_in[10];
    const float* Wtd  = (const float*)d_in[11];
    const float* btd  = (const float*)d_in[12];
    const float* Wfc1 = (const float*)d_in[13];
    const float* bfc1 = (const float*)d_in[14];
    const float* Wfc2 = (const float*)d_in[15];
    const float* bfc2 = (const float*)d_in[16];
    float* out = (float*)d_out;

    const size_t WSZ = (size_t)4 * HH * HH;      // 1M elems
    const size_t HFR = (size_t)32 * 16 * 64 * 8; // 262144 elems
    const size_t HSZ = (size_t)BB * HH;

    char* pp = (char*)d_ws;
    short* W0h = (short*)pp; pp += WSZ * 2;
    short* W0l = (short*)pp; pp += WSZ * 2;
    short* W1h = (short*)pp; pp += WSZ * 2;
    short* W1l = (short*)pp; pp += WSZ * 2;
    short* WIh = (short*)pp; pp += WSZ * 2;
    short* WIl = (short*)pp; pp += WSZ * 2;
    short* h0fh0 = (short*)pp; pp += HFR * 2;
    short* h0fl0 = (short*)pp; pp += HFR * 2;
    short* h0fh1 = (short*)pp; pp += HFR * 2;
    short* h0fl1 = (short*)pp; pp += HFR * 2;
    short* h1fh0 = (short*)pp; pp += HFR * 2;
    short* h1fl0 = (short*)pp; pp += HFR * 2;
    short* h1fh1 = (short*)pp; pp += HFR * 2;
    short* h1fl1 = (short*)pp; pp += HFR * 2;
    float* H0f = (float*)pp; pp += HSZ * 4;
    float* H1f = (float*)pp; pp += HSZ * 4;
    float* TD  = (float*)pp; pp += (size_t)BB * TDN * 4;
    unsigned* sync = (unsigned*)pp; pp += 512 * 4;

    // one-time (per call) weight/state conversion to fragment layouts
    cvt_wfrag<<<dim3(512), dim3(256), 0, stream>>>(Whh0, W0h, W0l);
    cvt_wfrag<<<dim3(512), dim3(256), 0, stream>>>(Whh1, W1h, W1l);
    cvt_wfrag<<<dim3(512), dim3(256), 0, stream>>>(Wih1, WIh, WIl);
    cvt_hfrag<<<dim3(128), dim3(256), 0, stream>>>(h0,        h0fh0, h0fl0);   // layer0 init -> parity 0
    cvt_hfrag<<<dim3(128), dim3(256), 0, stream>>>(h0 + HSZ,  h1fh1, h1fl1);   // layer1 init -> parity 1
    zero_sync<<<dim3(1), dim3(512), 0, stream>>>(sync);

    lstm_persist<<<dim3(NBLK), dim3(512), 0, stream>>>(
        W0h, W0l, W1h, W1l, WIh, WIl,
        Wih0, x, bih0, bhh0, bih1, bhh1, c0,
        h0fh0, h0fl0, h0fh1, h0fl1,
        h1fh0, h1fl0, h1fh1, h1fl1,
        H0f, H1f, sync);

    const dim3 gtd(TDN / TN, BB / TM);
    td_kernel<<<gtd, dim3(256), 0, stream>>>(H0f, H1f, Wtd, btd, TD);
    fc_kernel<<<dim3(BB / 32), dim3(256), 0, stream>>>(TD, Wfc1, bfc1, Wfc2, bfc2, out);

    (void)in_sizes; (void)n_in; (void)out_size; (void)ws_size;
}

// Round 6
// 9958.399 us; speedup vs baseline: 1.8665x; 1.2033x over previous
//
#include <hip/hip_runtime.h>
#include <math.h>

#define BB 512
#define HH 512
#define SS 256
#define XD0 3
#define TDN 256
#define FC1N 20
#define OUTN 2
#define TM 32
#define TN 32
#define TK 32
#define NBLK 256   // persistent grid size (== #CUs; 1 block/CU guaranteed co-resident)

typedef __attribute__((ext_vector_type(8))) short short8;
typedef __attribute__((ext_vector_type(4))) short short4v;
typedef __attribute__((ext_vector_type(4))) float f32x4;
typedef unsigned long long u64;

__device__ __forceinline__ unsigned short bf16_rne(float f) {
    unsigned u = __float_as_uint(f);
    u += 0x7FFFu + ((u >> 16) & 1u);
    return (unsigned short)(u >> 16);
}
__device__ __forceinline__ float bf16_to_f(unsigned short h) {
    return __uint_as_float(((unsigned)h) << 16);
}
__device__ __forceinline__ float sigmoid_(float x) { return 1.0f / (1.0f + __expf(-x)); }
__device__ __forceinline__ float tanh_(float x) {
    float e = __expf(2.0f * x);
    return 1.0f - 2.0f / (e + 1.0f);
}

// Coherent (agent-scope, L2-bypass sc1) 16B load as 2x 8B relaxed atomics.
// Compiler tracks vmcnt itself -> full ILP, no per-load waitcnt.
__device__ __forceinline__ short8 cload8(const short* p) {
    u64 a = __hip_atomic_load((const u64*)p,     __ATOMIC_RELAXED, __HIP_MEMORY_SCOPE_AGENT);
    u64 b = __hip_atomic_load((const u64*)p + 1, __ATOMIC_RELAXED, __HIP_MEMORY_SCOPE_AGENT);
    union { u64 q[2]; short8 v; } u;
    u.q[0] = a; u.q[1] = b;
    return u.v;
}
// Coherent 8B store (write-through to coherence point).
__device__ __forceinline__ void cstore4(short* p, short4v v) {
    u64 q; __builtin_memcpy(&q, &v, 8);
    __hip_atomic_store((u64*)p, q, __ATOMIC_RELAXED, __HIP_MEMORY_SCOPE_AGENT);
}

// ---- weights fp32 [4H][H] -> MFMA B-frag layout [jt32][g4][kt16][lane64][e8], hi+lo split
__global__ __launch_bounds__(256)
void cvt_wfrag(const float* __restrict__ W, short* __restrict__ hi, short* __restrict__ lo)
{
    int idx = blockIdx.x * 256 + threadIdx.x;   // 0..131071
    int l   = idx & 63;
    int kt  = (idx >> 6) & 15;
    int g   = (idx >> 10) & 3;
    int jt  = idx >> 12;
    int row = g * HH + jt * 16 + (l & 15);
    int col = kt * 32 + (l >> 4) * 8;
    size_t src = (size_t)row * HH + col;
    size_t dst = (size_t)idx * 8;
    #pragma unroll
    for (int e = 0; e < 8; ++e) {
        float v = W[src + e];
        unsigned short h = bf16_rne(v);
        hi[dst + e] = (short)h;
        lo[dst + e] = (short)bf16_rne(v - bf16_to_f(h));
    }
}

// ---- initial h fp32 [r][k] -> A-frag layout [rt32][kt16][lane64][e8], hi+lo split
__global__ __launch_bounds__(256)
void cvt_hfrag(const float* __restrict__ Hsrc, short* __restrict__ hi, short* __restrict__ lo)
{
    int idx = blockIdx.x * 256 + threadIdx.x;   // 0..32767
    int l  = idx & 63;
    int kt = (idx >> 6) & 15;
    int rt = idx >> 10;
    int r = rt * 16 + (l & 15);
    int k = kt * 32 + (l >> 4) * 8;
    size_t src = (size_t)r * HH + k;
    size_t dst = (size_t)idx * 8;
    #pragma unroll
    for (int e = 0; e < 8; ++e) {
        float v = Hsrc[src + e];
        unsigned short h = bf16_rne(v);
        hi[dst + e] = (short)h;
        lo[dst + e] = (short)bf16_rne(v - bf16_to_f(h));
    }
}

__global__ void zero_sync(unsigned* s) { s[threadIdx.x] = 0u; }   // 512 threads

// ---- grid barrier: tree arrival (8 groups x 32, one line each), monotonic counters.
// NO cache-maintenance fences at all: h-frag data moves via sc1 write-through
// stores / sc1 bypass loads (cload8/cstore4), so L2 never needs invalidating.
// Release ordering: __syncthreads() drains each wave's vmcnt before the arrival
// RMW is issued -> arrival visible only after all this block's data stores are
// visible at the coherence point. Acquire: poller's data loads bypass L2.
__device__ __forceinline__ void grid_barrier(unsigned* sync, int p, int bid)
{
    __syncthreads();
    if (threadIdx.x == 0) {
        const int g = bid & 7;
        unsigned a = __hip_atomic_fetch_add(&sync[g * 32], 1u,
                        __ATOMIC_RELAXED, __HIP_MEMORY_SCOPE_AGENT);
        if (a == (unsigned)((NBLK / 8) * (p + 1) - 1)) {
            unsigned r = __hip_atomic_fetch_add(&sync[256], 1u,
                            __ATOMIC_RELAXED, __HIP_MEMORY_SCOPE_AGENT);
            if (r == (unsigned)(8 * (p + 1) - 1)) {
                __hip_atomic_store(&sync[320], (unsigned)(p + 1),
                                   __ATOMIC_RELAXED, __HIP_MEMORY_SCOPE_AGENT);
            }
        }
        while (__hip_atomic_load(&sync[320], __ATOMIC_RELAXED,
                                 __HIP_MEMORY_SCOPE_AGENT) < (unsigned)(p + 1)) {
            __builtin_amdgcn_s_sleep(2);
        }
    }
    __syncthreads();
}

// K-split(8) LDS tree reduction + fused LSTM cell epilogue (c-state in registers).
// acc tiles: acc[rt][g], C-frag: row_local = rt*16 + (l>>4)*4 + q, col = l&15
template<int LAYER>
__device__ __forceinline__ void reduce_epilogue(
    f32x4 (&acc)[4][4], float (*quad)[4096],
    int kh, int l, int tid, int jt, int rblk, int p,
    const float* __restrict__ sbias,   // LDS: [g*16 + jl] = bih+bhh for this block's j
    const float* __restrict__ swin,    // LDS: [(g*16+jl)*3 + d] Wih0 slice (layer0)
    const float* __restrict__ cinit,   // non-null only on this layer's first phase
    f32x4& cstate,
    short* __restrict__ hfh, short* __restrict__ hfl,
    float* __restrict__ Hf,
    const float* __restrict__ x)
{
    // round A: kh 4..7 -> quad[kh-4]
    if (kh >= 4) {
        #pragma unroll
        for (int rt = 0; rt < 4; ++rt)
            #pragma unroll
            for (int g = 0; g < 4; ++g)
                #pragma unroll
                for (int q = 0; q < 4; ++q)
                    quad[kh - 4][(g*64 + rt*16 + (l>>4)*4 + q)*16 + (l&15)] = acc[rt][g][q];
    }
    __syncthreads();
    if (kh < 4) {
        #pragma unroll
        for (int rt = 0; rt < 4; ++rt)
            #pragma unroll
            for (int g = 0; g < 4; ++g)
                #pragma unroll
                for (int q = 0; q < 4; ++q)
                    acc[rt][g][q] += quad[kh][(g*64 + rt*16 + (l>>4)*4 + q)*16 + (l&15)];
    }
    __syncthreads();
    if (kh == 2 || kh == 3) {
        #pragma unroll
        for (int rt = 0; rt < 4; ++rt)
            #pragma unroll
            for (int g = 0; g < 4; ++g)
                #pragma unroll
                for (int q = 0; q < 4; ++q)
                    quad[kh][(g*64 + rt*16 + (l>>4)*4 + q)*16 + (l&15)] = acc[rt][g][q];
    }
    __syncthreads();
    if (kh == 0 || kh == 1) {
        #pragma unroll
        for (int rt = 0; rt < 4; ++rt)
            #pragma unroll
            for (int g = 0; g < 4; ++g)
                #pragma unroll
                for (int q = 0; q < 4; ++q)
                    acc[rt][g][q] += quad[kh + 2][(g*64 + rt*16 + (l>>4)*4 + q)*16 + (l&15)];
        if (kh == 1) {
            #pragma unroll
            for (int rt = 0; rt < 4; ++rt)
                #pragma unroll
                for (int g = 0; g < 4; ++g)
                    #pragma unroll
                    for (int q = 0; q < 4; ++q)
                        quad[1][(g*64 + rt*16 + (l>>4)*4 + q)*16 + (l&15)] = acc[rt][g][q];
        }
    }
    __syncthreads();
    if (kh == 0) {
        #pragma unroll
        for (int rt = 0; rt < 4; ++rt)
            #pragma unroll
            for (int g = 0; g < 4; ++g) {
                #pragma unroll
                for (int q = 0; q < 4; ++q) {
                    acc[rt][g][q] += quad[1][(g*64 + rt*16 + (l>>4)*4 + q)*16 + (l&15)];
                    quad[0][(g*64 + rt*16 + (l>>4)*4 + q)*16 + (l&15)] = acc[rt][g][q];
                }
            }
    }
    __syncthreads();

    // epilogue: 256 threads, each (row, j-quad); c-state lives in this thread's registers
    if (tid < 256) {
        const int rl = tid >> 2;
        const int jl = (tid & 3) * 4;
        const int r  = rblk * 64 + rl;
        const int j  = jt * 16 + jl;
        f32x4 gv[4];
        #pragma unroll
        for (int g = 0; g < 4; ++g) {
            gv[g] = *(const f32x4*)&quad[0][(g*64 + rl)*16 + jl];
            f32x4 bv = *(const f32x4*)&sbias[g*16 + jl];
            #pragma unroll
            for (int q = 0; q < 4; ++q) gv[g][q] += bv[q];
        }
        if (LAYER == 0) {
            const float x0 = x[(size_t)p * BB * XD0 + r * XD0 + 0];
            const float x1 = x[(size_t)p * BB * XD0 + r * XD0 + 1];
            const float x2 = x[(size_t)p * BB * XD0 + r * XD0 + 2];
            #pragma unroll
            for (int g = 0; g < 4; ++g)
                #pragma unroll
                for (int e = 0; e < 4; ++e) {
                    const float* wr_ = &swin[(g*16 + jl + e) * 3];
                    gv[g][e] += x0 * wr_[0] + x1 * wr_[1] + x2 * wr_[2];
                }
        }
        f32x4 cv = cstate;
        if (cinit != nullptr) cv = *(const f32x4*)&cinit[(size_t)r * HH + j];
        float hn[4];
        #pragma unroll
        for (int e = 0; e < 4; ++e) {
            float I = sigmoid_(gv[0][e]);
            float F = sigmoid_(gv[1][e]);
            float G = tanh_(gv[2][e]);
            float O = sigmoid_(gv[3][e]);
            float cn = F * cv[e] + I * G;
            cv[e] = cn;
            hn[e] = O * tanh_(cn);
        }
        cstate = cv;
        // h -> A-frag layout (4 bf16 hi + 4 lo, 8B each) via coherent write-through
        const int ktj   = j >> 5;
        const int lanew = (r & 15) | (((j & 31) >> 3) << 4);
        const int e0    = j & 7;      // 0 or 4
        const int rtg   = r >> 4;
        size_t hoff = ((((size_t)rtg)*16 + ktj)*64 + lanew)*8 + e0;
        short4v hhi, hlo;
        #pragma unroll
        for (int e = 0; e < 4; ++e) {
            unsigned short hb = bf16_rne(hn[e]);
            hhi[e] = (short)hb;
            hlo[e] = (short)bf16_rne(hn[e] - bf16_to_f(hb));
        }
        cstore4(&hfh[hoff], hhi);
        cstore4(&hfl[hoff], hlo);
        if (Hf != nullptr) {
            f32x4 hv;
            #pragma unroll
            for (int e = 0; e < 4; ++e) hv[e] = hn[e];
            *(f32x4*)&Hf[(size_t)r * HH + j] = hv;
        }
    }
    __syncthreads();   // protect quad reuse
}

__global__ __launch_bounds__(512, 2)
void lstm_persist(
    const short* __restrict__ W0h, const short* __restrict__ W0l,
    const short* __restrict__ W1h, const short* __restrict__ W1l,
    const short* __restrict__ WIh, const short* __restrict__ WIl,
    const float* __restrict__ Wih0, const float* __restrict__ x,
    const float* __restrict__ bih0, const float* __restrict__ bhh0,
    const float* __restrict__ bih1, const float* __restrict__ bhh1,
    const float* __restrict__ c0in,
    short* __restrict__ h0fh0, short* __restrict__ h0fl0,
    short* __restrict__ h0fh1, short* __restrict__ h0fl1,
    short* __restrict__ h1fh0, short* __restrict__ h1fl0,
    short* __restrict__ h1fh1, short* __restrict__ h1fl1,
    float* __restrict__ H0f, float* __restrict__ H1f,
    unsigned* __restrict__ sync)
{
    __shared__ float quad[4][4096];            // 64 KB
    __shared__ __align__(16) float sb[2][64];  // per-block bias sums (bih+bhh), both layers
    __shared__ float swin[192];                // per-block Wih0 slice [g*16+jl][3]

    const int tid  = threadIdx.x;
    const int kh   = tid >> 6;
    const int l    = tid & 63;
    const int bid  = blockIdx.x;
    const int jt   = bid & 31;        // XCD = bid%8 -> same-j weights per XCD
    const int rblk = bid >> 5;

    // one-time LDS preload of bias sums + Wih0 slice (L2 stays warm: no invalidates)
    if (tid < 128) {
        const int L = tid >> 6;
        const int gj = tid & 63;
        const int g = gj >> 4, jl = gj & 15;
        const int j = jt * 16 + jl;
        const float* bi = L ? bih1 : bih0;
        const float* bh = L ? bhh1 : bhh0;
        sb[L][gj] = bi[g * HH + j] + bh[g * HH + j];
    } else if (tid < 320) {
        const int q = tid - 128;            // 0..191
        const int gj = q / 3, d = q - gj * 3;
        const int g = gj >> 4, jl = gj & 15;
        const int j = jt * 16 + jl;
        swin[q] = Wih0[(size_t)(g * HH + j) * XD0 + d];
    }

    // persistent B_hi fragments (96 VGPRs)
    short8 b0h[2][4];
    short8 b1h[4][4];
    #pragma unroll
    for (int kk = 0; kk < 2; ++kk)
        #pragma unroll
        for (int g = 0; g < 4; ++g)
            b0h[kk][g] = *(const short8*)&W0h[((((size_t)jt*4 + g)*16 + (kh + kk*8))*64 + l)*8];
    #pragma unroll
    for (int kk = 0; kk < 4; ++kk)
        #pragma unroll
        for (int g = 0; g < 4; ++g) {
            const short* Wh = (kk < 2) ? W1h : WIh;
            const int kt = kh + (kk & 1) * 8;
            b1h[kk][g] = *(const short8*)&Wh[((((size_t)jt*4 + g)*16 + kt)*64 + l)*8];
        }

    // per-thread recurrent c-state (valid for tid<256)
    f32x4 c0reg, c1reg;
    #pragma unroll
    for (int e = 0; e < 4; ++e) { c0reg[e] = 0.0f; c1reg[e] = 0.0f; }

    __syncthreads();   // LDS preload visible

    for (int p = 0; p <= SS; ++p) {
        const int par = p & 1;
        // ---------------- layer 0, step p ----------------
        if (p < SS) {
            const short* Ah = par ? h0fh1 : h0fh0;
            const short* Al = par ? h0fl1 : h0fl0;
            f32x4 acc[4][4];
            #pragma unroll
            for (int rt = 0; rt < 4; ++rt)
                #pragma unroll
                for (int g = 0; g < 4; ++g)
                    #pragma unroll
                    for (int q = 0; q < 4; ++q) acc[rt][g][q] = 0.0f;
            #pragma unroll
            for (int kk = 0; kk < 2; ++kk) {
                const int kt = kh + kk * 8;
                short8 bl[4];
                #pragma unroll
                for (int g = 0; g < 4; ++g)
                    bl[g] = *(const short8*)&W0l[((((size_t)jt*4 + g)*16 + kt)*64 + l)*8];
                #pragma unroll
                for (int rt = 0; rt < 4; ++rt) {
                    const size_t ab = ((((size_t)(rblk*4 + rt))*16 + kt)*64 + l)*8;
                    short8 ah = cload8(&Ah[ab]);
                    short8 al = cload8(&Al[ab]);
                    #pragma unroll
                    for (int g = 0; g < 4; ++g) {
                        acc[rt][g] = __builtin_amdgcn_mfma_f32_16x16x32_bf16(ah, b0h[kk][g], acc[rt][g], 0,0,0);
                        acc[rt][g] = __builtin_amdgcn_mfma_f32_16x16x32_bf16(ah, bl[g],      acc[rt][g], 0,0,0);
                        acc[rt][g] = __builtin_amdgcn_mfma_f32_16x16x32_bf16(al, b0h[kk][g], acc[rt][g], 0,0,0);
                    }
                }
            }
            reduce_epilogue<0>(acc, quad, kh, l, tid, jt, rblk, p,
                               sb[0], swin,
                               (p == 0) ? c0in : nullptr, c0reg,
                               par ? h0fh0 : h0fh1, par ? h0fl0 : h0fl1,
                               (p == SS - 1) ? H0f : nullptr, x);
        }
        // ---------------- layer 1, step p-1 ----------------
        if (p >= 1) {
            const short* A1h = par ? h1fh1 : h1fh0;
            const short* A1l = par ? h1fl1 : h1fl0;
            const short* Y0h = par ? h0fh1 : h0fh0;
            const short* Y0l = par ? h0fl1 : h0fl0;
            f32x4 acc[4][4];
            #pragma unroll
            for (int rt = 0; rt < 4; ++rt)
                #pragma unroll
                for (int g = 0; g < 4; ++g)
                    #pragma unroll
                    for (int q = 0; q < 4; ++q) acc[rt][g][q] = 0.0f;
            #pragma unroll
            for (int kk = 0; kk < 4; ++kk) {
                const int kt = kh + (kk & 1) * 8;
                const short* Ah = (kk < 2) ? A1h : Y0h;
                const short* Al = (kk < 2) ? A1l : Y0l;
                const short* Wl = (kk < 2) ? W1l : WIl;
                short8 bl[4];
                #pragma unroll
                for (int g = 0; g < 4; ++g)
                    bl[g] = *(const short8*)&Wl[((((size_t)jt*4 + g)*16 + kt)*64 + l)*8];
                #pragma unroll
                for (int rt = 0; rt < 4; ++rt) {
                    const size_t ab = ((((size_t)(rblk*4 + rt))*16 + kt)*64 + l)*8;
                    short8 ah = cload8(&Ah[ab]);
                    short8 al = cload8(&Al[ab]);
                    #pragma unroll
                    for (int g = 0; g < 4; ++g) {
                        acc[rt][g] = __builtin_amdgcn_mfma_f32_16x16x32_bf16(ah, b1h[kk][g], acc[rt][g], 0,0,0);
                        acc[rt][g] = __builtin_amdgcn_mfma_f32_16x16x32_bf16(ah, bl[g],      acc[rt][g], 0,0,0);
                        acc[rt][g] = __builtin_amdgcn_mfma_f32_16x16x32_bf16(al, b1h[kk][g], acc[rt][g], 0,0,0);
                    }
                }
            }
            reduce_epilogue<1>(acc, quad, kh, l, tid, jt, rblk, p,
                               sb[1], swin,
                               (p == 1) ? (c0in + (size_t)BB*HH) : nullptr, c1reg,
                               par ? h1fh0 : h1fh1, par ? h1fl0 : h1fl1,
                               (p == SS) ? H1f : nullptr, x);
        }
        grid_barrier(sync, p, bid);
    }
}

// td[b][s] = btd[s] + cat(h0T,h1T)[b][:] . Wtd[s][:]  (validated R1/R2)
__global__ __launch_bounds__(256)
void td_kernel(const float* __restrict__ h0T, const float* __restrict__ h1T,
               const float* __restrict__ Wtd, const float* __restrict__ btd,
               float* __restrict__ td)
{
    __shared__ float a_lds[TM][TK + 1];
    __shared__ float b_lds[TN][TK + 1];
    const int t = threadIdx.x;
    const int nl = t & 31;
    const int mq = t >> 5;
    const int n0 = blockIdx.x * TN;
    const int m0 = blockIdx.y * TM;
    float acc[4] = {0.f, 0.f, 0.f, 0.f};

    for (int k0 = 0; k0 < 2 * HH; k0 += TK) {
        const float* src = (k0 < HH) ? h0T : h1T;
        int kb = k0 & (HH - 1);
        #pragma unroll
        for (int i = 0; i < (TM * TK) / 256; ++i) {
            int idx = t + i * 256;
            int r = idx >> 5, kk = idx & 31;
            a_lds[r][kk] = src[(size_t)(m0 + r) * HH + kb + kk];
        }
        #pragma unroll
        for (int i = 0; i < (TN * TK) / 256; ++i) {
            int idx = t + i * 256;
            int jn = idx >> 5, kk = idx & 31;
            b_lds[jn][kk] = Wtd[(size_t)(n0 + jn) * (2 * HH) + k0 + kk];
        }
        __syncthreads();
        #pragma unroll
        for (int kk = 0; kk < TK; ++kk) {
            float bv = b_lds[nl][kk];
            #pragma unroll
            for (int rr = 0; rr < 4; ++rr)
                acc[rr] = fmaf(a_lds[mq * 4 + rr][kk], bv, acc[rr]);
        }
        __syncthreads();
    }
    #pragma unroll
    for (int rr = 0; rr < 4; ++rr)
        td[(size_t)(m0 + mq * 4 + rr) * TDN + n0 + nl] = acc[rr] + btd[n0 + nl];
}

__global__ __launch_bounds__(256)
void fc_kernel(const float* __restrict__ td,
               const float* __restrict__ Wfc1, const float* __restrict__ bfc1,
               const float* __restrict__ Wfc2, const float* __restrict__ bfc2,
               float* __restrict__ out)
{
    __shared__ float td_lds[32][TDN];
    __shared__ float f1_lds[32][FC1N];
    const int t = threadIdx.x;
    const int r0 = blockIdx.x * 32;

    #pragma unroll
    for (int i = 0; i < (32 * TDN) / 256; ++i) {
        int idx = t + i * 256;
        int r = idx >> 8, k = idx & 255;
        td_lds[r][k] = td[(size_t)(r0 + r) * TDN + k];
    }
    __syncthreads();

    for (int idx = t; idx < 32 * FC1N; idx += 256) {
        int r = idx / FC1N, o = idx % FC1N;
        float s = bfc1[o];
        for (int k = 0; k < TDN; ++k) s = fmaf(td_lds[r][k], Wfc1[o * TDN + k], s);
        f1_lds[r][o] = fmaxf(s, 0.0f);
    }
    __syncthreads();

    for (int idx = t; idx < 32 * OUTN; idx += 256) {
        int r = idx / OUTN, o = idx % OUTN;
        float s = bfc2[o];
        for (int k = 0; k < FC1N; ++k) s = fmaf(f1_lds[r][k], Wfc2[o * FC1N + k], s);
        out[(size_t)(r0 + r) * OUTN + o] = s;
    }
}

extern "C" void kernel_launch(void* const* d_in, const int* in_sizes, int n_in,
                              void* d_out, int out_size, void* d_ws, size_t ws_size,
                              hipStream_t stream)
{
    const float* x    = (const float*)d_in[0];
    const float* h0   = (const float*)d_in[1];
    const float* c0   = (const float*)d_in[2];
    const float* Wih0 = (const float*)d_in[3];
    const float* Whh0 = (const float*)d_in[4];
    const float* bih0 = (const float*)d_in[5];
    const float* bhh0 = (const float*)d_in[6];
    const float* Wih1 = (const float*)d_in[7];
    const float* Whh1 = (const float*)d_in[8];
    const float* bih1 = (const float*)d_in[9];
    const float* bhh1 = (const float*)d_in[10];
    const float* Wtd  = (const float*)d_in[11];
    const float* btd  = (const float*)d_in[12];
    const float* Wfc1 = (const float*)d_in[13];
    const float* bfc1 = (const float*)d_in[14];
    const float* Wfc2 = (const float*)d_in[15];
    const float* bfc2 = (const float*)d_in[16];
    float* out = (float*)d_out;

    const size_t WSZ = (size_t)4 * HH * HH;      // 1M elems
    const size_t HFR = (size_t)32 * 16 * 64 * 8; // 262144 elems
    const size_t HSZ = (size_t)BB * HH;

    char* pp = (char*)d_ws;
    short* W0h = (short*)pp; pp += WSZ * 2;
    short* W0l = (short*)pp; pp += WSZ * 2;
    short* W1h = (short*)pp; pp += WSZ * 2;
    short* W1l = (short*)pp; pp += WSZ * 2;
    short* WIh = (short*)pp; pp += WSZ * 2;
    short* WIl = (short*)pp; pp += WSZ * 2;
    short* h0fh0 = (short*)pp; pp += HFR * 2;
    short* h0fl0 = (short*)pp; pp += HFR * 2;
    short* h0fh1 = (short*)pp; pp += HFR * 2;
    short* h0fl1 = (short*)pp; pp += HFR * 2;
    short* h1fh0 = (short*)pp; pp += HFR * 2;
    short* h1fl0 = (short*)pp; pp += HFR * 2;
    short* h1fh1 = (short*)pp; pp += HFR * 2;
    short* h1fl1 = (short*)pp; pp += HFR * 2;
    float* H0f = (float*)pp; pp += HSZ * 4;
    float* H1f = (float*)pp; pp += HSZ * 4;
    float* TD  = (float*)pp; pp += (size_t)BB * TDN * 4;
    unsigned* sync = (unsigned*)pp; pp += 512 * 4;

    // one-time (per call) weight/state conversion to fragment layouts
    cvt_wfrag<<<dim3(512), dim3(256), 0, stream>>>(Whh0, W0h, W0l);
    cvt_wfrag<<<dim3(512), dim3(256), 0, stream>>>(Whh1, W1h, W1l);
    cvt_wfrag<<<dim3(512), dim3(256), 0, stream>>>(Wih1, WIh, WIl);
    cvt_hfrag<<<dim3(128), dim3(256), 0, stream>>>(h0,        h0fh0, h0fl0);   // layer0 init -> parity 0
    cvt_hfrag<<<dim3(128), dim3(256), 0, stream>>>(h0 + HSZ,  h1fh1, h1fl1);   // layer1 init -> parity 1
    zero_sync<<<dim3(1), dim3(512), 0, stream>>>(sync);

    lstm_persist<<<dim3(NBLK), dim3(512), 0, stream>>>(
        W0h, W0l, W1h, W1l, WIh, WIl,
        Wih0, x, bih0, bhh0, bih1, bhh1, c0,
        h0fh0, h0fl0, h0fh1, h0fl1,
        h1fh0, h1fl0, h1fh1, h1fl1,
        H0f, H1f, sync);

    const dim3 gtd(TDN / TN, BB / TM);
    td_kernel<<<gtd, dim3(256), 0, stream>>>(H0f, H1f, Wtd, btd, TD);
    fc_kernel<<<dim3(BB / 32), dim3(256), 0, stream>>>(TD, Wfc1, bfc1, Wfc2, bfc2, out);

    (void)in_sizes; (void)n_in; (void)out_size; (void)ws_size;
}

// Round 7
// 9291.480 us; speedup vs baseline: 2.0005x; 1.0718x over previous
//
#include <hip/hip_runtime.h>
#include <math.h>

#define BB 512
#define HH 512
#define SS 256
#define XD0 3
#define TDN 256
#define FC1N 20
#define OUTN 2
#define TM 32
#define TN 32
#define TK 32
#define NBLK 256   // persistent grid size (== #CUs; 1 block/CU by VGPR footprint)

typedef __attribute__((ext_vector_type(8))) short short8;
typedef __attribute__((ext_vector_type(4))) short short4v;
typedef __attribute__((ext_vector_type(4))) float f32x4;
typedef unsigned long long u64;

// sync[] layout (u32 indices):
//   0..255   global tree group counters (g*32)
//   256      global tree root
//   320      global tree generation
//   384..391 per-XCD claim counters
//   416      detect-barrier counter
//   448      detect-barrier generation
//   512+x*64 per-XCD barrier counter ; 512+x*64+32 per-XCD generation
#define SYNC_WORDS 1024

__device__ __forceinline__ unsigned short bf16_rne(float f) {
    unsigned u = __float_as_uint(f);
    u += 0x7FFFu + ((u >> 16) & 1u);
    return (unsigned short)(u >> 16);
}
__device__ __forceinline__ float bf16_to_f(unsigned short h) {
    return __uint_as_float(((unsigned)h) << 16);
}
__device__ __forceinline__ float sigmoid_(float x) { return 1.0f / (1.0f + __expf(-x)); }
__device__ __forceinline__ float tanh_(float x) {
    float e = __expf(2.0f * x);
    return 1.0f - 2.0f / (e + 1.0f);
}

// Coherent (agent-scope, L2-bypass) 16B load as 2x 8B relaxed atomics (R6 fallback path).
__device__ __forceinline__ short8 cload8(const short* p) {
    u64 a = __hip_atomic_load((const u64*)p,     __ATOMIC_RELAXED, __HIP_MEMORY_SCOPE_AGENT);
    u64 b = __hip_atomic_load((const u64*)p + 1, __ATOMIC_RELAXED, __HIP_MEMORY_SCOPE_AGENT);
    union { u64 q[2]; short8 v; } u;
    u.q[0] = a; u.q[1] = b;
    return u.v;
}
__device__ __forceinline__ void cstore4(short* p, short4v v) {
    u64 q; __builtin_memcpy(&q, &v, 8);
    __hip_atomic_store((u64*)p, q, __ATOMIC_RELAXED, __HIP_MEMORY_SCOPE_AGENT);
}

// A-frag load / h-frag store, selected by coherence mode.
// COH=false (XCD-local mode): plain cached ops — coherent through the XCD's own L2.
// COH=true  (fallback): sc1 bypass ops — globally coherent regardless of placement.
template<bool COH> __device__ __forceinline__ short8 ald(const short* p) {
    if constexpr (COH) return cload8(p);
    else return *(const short8*)p;
}
template<bool COH> __device__ __forceinline__ void ast(short* p, short4v v) {
    if constexpr (COH) cstore4(p, v);
    else *(short4v*)p = v;
}

// ---- weights fp32 [4H][H] -> MFMA B-frag layout [jt32][g4][kt16][lane64][e8], hi+lo split
__global__ __launch_bounds__(256)
void cvt_wfrag(const float* __restrict__ W, short* __restrict__ hi, short* __restrict__ lo)
{
    int idx = blockIdx.x * 256 + threadIdx.x;   // 0..131071
    int l   = idx & 63;
    int kt  = (idx >> 6) & 15;
    int g   = (idx >> 10) & 3;
    int jt  = idx >> 12;
    int row = g * HH + jt * 16 + (l & 15);
    int col = kt * 32 + (l >> 4) * 8;
    size_t src = (size_t)row * HH + col;
    size_t dst = (size_t)idx * 8;
    #pragma unroll
    for (int e = 0; e < 8; ++e) {
        float v = W[src + e];
        unsigned short h = bf16_rne(v);
        hi[dst + e] = (short)h;
        lo[dst + e] = (short)bf16_rne(v - bf16_to_f(h));
    }
}

// ---- initial h fp32 [r][k] -> A-frag layout [rt32][kt16][lane64][e8], hi+lo split
__global__ __launch_bounds__(256)
void cvt_hfrag(const float* __restrict__ Hsrc, short* __restrict__ hi, short* __restrict__ lo)
{
    int idx = blockIdx.x * 256 + threadIdx.x;   // 0..32767
    int l  = idx & 63;
    int kt = (idx >> 6) & 15;
    int rt = idx >> 10;
    int r = rt * 16 + (l & 15);
    int k = kt * 32 + (l >> 4) * 8;
    size_t src = (size_t)r * HH + k;
    size_t dst = (size_t)idx * 8;
    #pragma unroll
    for (int e = 0; e < 8; ++e) {
        float v = Hsrc[src + e];
        unsigned short h = bf16_rne(v);
        hi[dst + e] = (short)h;
        lo[dst + e] = (short)bf16_rne(v - bf16_to_f(h));
    }
}

__global__ void zero_sync(unsigned* s) { s[blockIdx.x * 256 + threadIdx.x] = 0u; }

// Phase barrier. COH=true: R6 global tree over 256 blocks. COH=false: per-XCD
// barrier over the 32 blocks sharing rblk (== physical XCD) — no cross-XCD coupling.
// No cache-maintenance fences in either mode: data ops are coherent by construction
// (plain ops within one L2, or sc1 bypass). __syncthreads drains vmcnt before arrival.
template<bool COH>
__device__ __forceinline__ void phase_barrier(unsigned* sync, int p, int bid, int rblk)
{
    __syncthreads();
    if (threadIdx.x == 0) {
        if constexpr (COH) {
            const int g = bid & 7;
            unsigned a = __hip_atomic_fetch_add(&sync[g * 32], 1u,
                            __ATOMIC_RELAXED, __HIP_MEMORY_SCOPE_AGENT);
            if (a == (unsigned)((NBLK / 8) * (p + 1) - 1)) {
                unsigned r = __hip_atomic_fetch_add(&sync[256], 1u,
                                __ATOMIC_RELAXED, __HIP_MEMORY_SCOPE_AGENT);
                if (r == (unsigned)(8 * (p + 1) - 1)) {
                    __hip_atomic_store(&sync[320], (unsigned)(p + 1),
                                       __ATOMIC_RELAXED, __HIP_MEMORY_SCOPE_AGENT);
                }
            }
            while (__hip_atomic_load(&sync[320], __ATOMIC_RELAXED,
                                     __HIP_MEMORY_SCOPE_AGENT) < (unsigned)(p + 1)) {
                __builtin_amdgcn_s_sleep(2);
            }
        } else {
            unsigned* cnt = &sync[512 + rblk * 64];
            unsigned* gen = &sync[512 + rblk * 64 + 32];
            unsigned a = __hip_atomic_fetch_add(cnt, 1u,
                            __ATOMIC_RELAXED, __HIP_MEMORY_SCOPE_AGENT);
            if (a == (unsigned)(32 * (p + 1) - 1)) {
                __hip_atomic_store(gen, (unsigned)(p + 1),
                                   __ATOMIC_RELAXED, __HIP_MEMORY_SCOPE_AGENT);
            }
            while (__hip_atomic_load(gen, __ATOMIC_RELAXED,
                                     __HIP_MEMORY_SCOPE_AGENT) < (unsigned)(p + 1)) {
                __builtin_amdgcn_s_sleep(1);
            }
        }
    }
    __syncthreads();
}

// K-split(8) LDS tree reduction + fused LSTM cell epilogue (c-state in registers).
template<int LAYER, bool COH>
__device__ __forceinline__ void reduce_epilogue(
    f32x4 (&acc)[4][4], float (*quad)[4096],
    int kh, int l, int tid, int jt, int rblk, int p,
    const float* __restrict__ sbias, const float* __restrict__ swin,
    const float* __restrict__ cinit, f32x4& cstate,
    short* __restrict__ hfh, short* __restrict__ hfl,
    float* __restrict__ Hf, const float* __restrict__ x)
{
    if (kh >= 4) {
        #pragma unroll
        for (int rt = 0; rt < 4; ++rt)
            #pragma unroll
            for (int g = 0; g < 4; ++g)
                #pragma unroll
                for (int q = 0; q < 4; ++q)
                    quad[kh - 4][(g*64 + rt*16 + (l>>4)*4 + q)*16 + (l&15)] = acc[rt][g][q];
    }
    __syncthreads();
    if (kh < 4) {
        #pragma unroll
        for (int rt = 0; rt < 4; ++rt)
            #pragma unroll
            for (int g = 0; g < 4; ++g)
                #pragma unroll
                for (int q = 0; q < 4; ++q)
                    acc[rt][g][q] += quad[kh][(g*64 + rt*16 + (l>>4)*4 + q)*16 + (l&15)];
    }
    __syncthreads();
    if (kh == 2 || kh == 3) {
        #pragma unroll
        for (int rt = 0; rt < 4; ++rt)
            #pragma unroll
            for (int g = 0; g < 4; ++g)
                #pragma unroll
                for (int q = 0; q < 4; ++q)
                    quad[kh][(g*64 + rt*16 + (l>>4)*4 + q)*16 + (l&15)] = acc[rt][g][q];
    }
    __syncthreads();
    if (kh == 0 || kh == 1) {
        #pragma unroll
        for (int rt = 0; rt < 4; ++rt)
            #pragma unroll
            for (int g = 0; g < 4; ++g)
                #pragma unroll
                for (int q = 0; q < 4; ++q)
                    acc[rt][g][q] += quad[kh + 2][(g*64 + rt*16 + (l>>4)*4 + q)*16 + (l&15)];
        if (kh == 1) {
            #pragma unroll
            for (int rt = 0; rt < 4; ++rt)
                #pragma unroll
                for (int g = 0; g < 4; ++g)
                    #pragma unroll
                    for (int q = 0; q < 4; ++q)
                        quad[1][(g*64 + rt*16 + (l>>4)*4 + q)*16 + (l&15)] = acc[rt][g][q];
        }
    }
    __syncthreads();
    if (kh == 0) {
        #pragma unroll
        for (int rt = 0; rt < 4; ++rt)
            #pragma unroll
            for (int g = 0; g < 4; ++g) {
                #pragma unroll
                for (int q = 0; q < 4; ++q) {
                    acc[rt][g][q] += quad[1][(g*64 + rt*16 + (l>>4)*4 + q)*16 + (l&15)];
                    quad[0][(g*64 + rt*16 + (l>>4)*4 + q)*16 + (l&15)] = acc[rt][g][q];
                }
            }
    }
    __syncthreads();

    if (tid < 256) {
        const int rl = tid >> 2;
        const int jl = (tid & 3) * 4;
        const int r  = rblk * 64 + rl;
        const int j  = jt * 16 + jl;
        f32x4 gv[4];
        #pragma unroll
        for (int g = 0; g < 4; ++g) {
            gv[g] = *(const f32x4*)&quad[0][(g*64 + rl)*16 + jl];
            f32x4 bv = *(const f32x4*)&sbias[g*16 + jl];
            #pragma unroll
            for (int q = 0; q < 4; ++q) gv[g][q] += bv[q];
        }
        if (LAYER == 0) {
            const float x0 = x[(size_t)p * BB * XD0 + r * XD0 + 0];
            const float x1 = x[(size_t)p * BB * XD0 + r * XD0 + 1];
            const float x2 = x[(size_t)p * BB * XD0 + r * XD0 + 2];
            #pragma unroll
            for (int g = 0; g < 4; ++g)
                #pragma unroll
                for (int e = 0; e < 4; ++e) {
                    const float* wr_ = &swin[(g*16 + jl + e) * 3];
                    gv[g][e] += x0 * wr_[0] + x1 * wr_[1] + x2 * wr_[2];
                }
        }
        f32x4 cv = cstate;
        if (cinit != nullptr) cv = *(const f32x4*)&cinit[(size_t)r * HH + j];
        float hn[4];
        #pragma unroll
        for (int e = 0; e < 4; ++e) {
            float I = sigmoid_(gv[0][e]);
            float F = sigmoid_(gv[1][e]);
            float G = tanh_(gv[2][e]);
            float O = sigmoid_(gv[3][e]);
            float cn = F * cv[e] + I * G;
            cv[e] = cn;
            hn[e] = O * tanh_(cn);
        }
        cstate = cv;
        const int ktj   = j >> 5;
        const int lanew = (r & 15) | (((j & 31) >> 3) << 4);
        const int e0    = j & 7;
        const int rtg   = r >> 4;
        size_t hoff = ((((size_t)rtg)*16 + ktj)*64 + lanew)*8 + e0;
        short4v hhi, hlo;
        #pragma unroll
        for (int e = 0; e < 4; ++e) {
            unsigned short hb = bf16_rne(hn[e]);
            hhi[e] = (short)hb;
            hlo[e] = (short)bf16_rne(hn[e] - bf16_to_f(hb));
        }
        ast<COH>(&hfh[hoff], hhi);
        ast<COH>(&hfl[hoff], hlo);
        if (Hf != nullptr) {
            f32x4 hv;
            #pragma unroll
            for (int e = 0; e < 4; ++e) hv[e] = hn[e];
            *(f32x4*)&Hf[(size_t)r * HH + j] = hv;
        }
    }
    __syncthreads();
}

// Main persistent body, templated on coherence mode.
template<bool COH>
__device__ __forceinline__ void run_main(
    int tid, int bid, int rblk, int jt,
    float (*quad)[4096], float (*sb)[64], float* swin,
    const short* W0h, const short* W0l,
    const short* W1h, const short* W1l,
    const short* WIh, const short* WIl,
    const float* Wih0, const float* x,
    const float* bih0, const float* bhh0,
    const float* bih1, const float* bhh1,
    const float* c0in,
    short* h0fh0, short* h0fl0, short* h0fh1, short* h0fl1,
    short* h1fh0, short* h1fl0, short* h1fh1, short* h1fl1,
    float* H0f, float* H1f, unsigned* sync)
{
    const int kh = tid >> 6;
    const int l  = tid & 63;

    // one-time LDS preload of bias sums + Wih0 slice
    if (tid < 128) {
        const int L = tid >> 6;
        const int gj = tid & 63;
        const int g = gj >> 4, jl = gj & 15;
        const int j = jt * 16 + jl;
        const float* bi = L ? bih1 : bih0;
        const float* bh = L ? bhh1 : bhh0;
        sb[L][gj] = bi[g * HH + j] + bh[g * HH + j];
    } else if (tid < 320) {
        const int q = tid - 128;
        const int gj = q / 3, d = q - gj * 3;
        const int g = gj >> 4, jl = gj & 15;
        const int j = jt * 16 + jl;
        swin[q] = Wih0[(size_t)(g * HH + j) * XD0 + d];
    }

    // persistent B_hi fragments (96 VGPRs)
    short8 b0h[2][4];
    short8 b1h[4][4];
    #pragma unroll
    for (int kk = 0; kk < 2; ++kk)
        #pragma unroll
        for (int g = 0; g < 4; ++g)
            b0h[kk][g] = *(const short8*)&W0h[((((size_t)jt*4 + g)*16 + (kh + kk*8))*64 + l)*8];
    #pragma unroll
    for (int kk = 0; kk < 4; ++kk)
        #pragma unroll
        for (int g = 0; g < 4; ++g) {
            const short* Wh = (kk < 2) ? W1h : WIh;
            const int kt = kh + (kk & 1) * 8;
            b1h[kk][g] = *(const short8*)&Wh[((((size_t)jt*4 + g)*16 + kt)*64 + l)*8];
        }

    f32x4 c0reg, c1reg;
    #pragma unroll
    for (int e = 0; e < 4; ++e) { c0reg[e] = 0.0f; c1reg[e] = 0.0f; }

    __syncthreads();

    for (int p = 0; p <= SS; ++p) {
        const int par = p & 1;
        // ---------------- layer 0, step p ----------------
        if (p < SS) {
            const short* Ah = par ? h0fh1 : h0fh0;
            const short* Al = par ? h0fl1 : h0fl0;
            f32x4 acc[4][4];
            #pragma unroll
            for (int rt = 0; rt < 4; ++rt)
                #pragma unroll
                for (int g = 0; g < 4; ++g)
                    #pragma unroll
                    for (int q = 0; q < 4; ++q) acc[rt][g][q] = 0.0f;
            #pragma unroll
            for (int kk = 0; kk < 2; ++kk) {
                const int kt = kh + kk * 8;
                short8 bl[4];
                #pragma unroll
                for (int g = 0; g < 4; ++g)
                    bl[g] = *(const short8*)&W0l[((((size_t)jt*4 + g)*16 + kt)*64 + l)*8];
                #pragma unroll
                for (int rt = 0; rt < 4; ++rt) {
                    const size_t ab = ((((size_t)(rblk*4 + rt))*16 + kt)*64 + l)*8;
                    short8 ah = ald<COH>(&Ah[ab]);
                    short8 al = ald<COH>(&Al[ab]);
                    #pragma unroll
                    for (int g = 0; g < 4; ++g) {
                        acc[rt][g] = __builtin_amdgcn_mfma_f32_16x16x32_bf16(ah, b0h[kk][g], acc[rt][g], 0,0,0);
                        acc[rt][g] = __builtin_amdgcn_mfma_f32_16x16x32_bf16(ah, bl[g],      acc[rt][g], 0,0,0);
                        acc[rt][g] = __builtin_amdgcn_mfma_f32_16x16x32_bf16(al, b0h[kk][g], acc[rt][g], 0,0,0);
                    }
                }
            }
            reduce_epilogue<0, COH>(acc, quad, kh, l, tid, jt, rblk, p,
                               sb[0], swin,
                               (p == 0) ? c0in : nullptr, c0reg,
                               par ? h0fh0 : h0fh1, par ? h0fl0 : h0fl1,
                               (p == SS - 1) ? H0f : nullptr, x);
        }
        // ---------------- layer 1, step p-1 ----------------
        if (p >= 1) {
            const short* A1h = par ? h1fh1 : h1fh0;
            const short* A1l = par ? h1fl1 : h1fl0;
            const short* Y0h = par ? h0fh1 : h0fh0;
            const short* Y0l = par ? h0fl1 : h0fl0;
            f32x4 acc[4][4];
            #pragma unroll
            for (int rt = 0; rt < 4; ++rt)
                #pragma unroll
                for (int g = 0; g < 4; ++g)
                    #pragma unroll
                    for (int q = 0; q < 4; ++q) acc[rt][g][q] = 0.0f;
            #pragma unroll
            for (int kk = 0; kk < 4; ++kk) {
                const int kt = kh + (kk & 1) * 8;
                const short* Ah = (kk < 2) ? A1h : Y0h;
                const short* Al = (kk < 2) ? A1l : Y0l;
                const short* Wl = (kk < 2) ? W1l : WIl;
                short8 bl[4];
                #pragma unroll
                for (int g = 0; g < 4; ++g)
                    bl[g] = *(const short8*)&Wl[((((size_t)jt*4 + g)*16 + kt)*64 + l)*8];
                #pragma unroll
                for (int rt = 0; rt < 4; ++rt) {
                    const size_t ab = ((((size_t)(rblk*4 + rt))*16 + kt)*64 + l)*8;
                    short8 ah = ald<COH>(&Ah[ab]);
                    short8 al = ald<COH>(&Al[ab]);
                    #pragma unroll
                    for (int g = 0; g < 4; ++g) {
                        acc[rt][g] = __builtin_amdgcn_mfma_f32_16x16x32_bf16(ah, b1h[kk][g], acc[rt][g], 0,0,0);
                        acc[rt][g] = __builtin_amdgcn_mfma_f32_16x16x32_bf16(ah, bl[g],      acc[rt][g], 0,0,0);
                        acc[rt][g] = __builtin_amdgcn_mfma_f32_16x16x32_bf16(al, b1h[kk][g], acc[rt][g], 0,0,0);
                    }
                }
            }
            reduce_epilogue<1, COH>(acc, quad, kh, l, tid, jt, rblk, p,
                               sb[1], swin,
                               (p == 1) ? (c0in + (size_t)BB*HH) : nullptr, c1reg,
                               par ? h1fh0 : h1fh1, par ? h1fl0 : h1fl1,
                               (p == SS) ? H1f : nullptr, x);
        }
        phase_barrier<COH>(sync, p, bid, rblk);
    }
}

__global__ __launch_bounds__(512, 2)
void lstm_persist(
    const short* __restrict__ W0h, const short* __restrict__ W0l,
    const short* __restrict__ W1h, const short* __restrict__ W1l,
    const short* __restrict__ WIh, const short* __restrict__ WIl,
    const float* __restrict__ Wih0, const float* __restrict__ x,
    const float* __restrict__ bih0, const float* __restrict__ bhh0,
    const float* __restrict__ bih1, const float* __restrict__ bhh1,
    const float* __restrict__ c0in,
    short* __restrict__ h0fh0, short* __restrict__ h0fl0,
    short* __restrict__ h0fh1, short* __restrict__ h0fl1,
    short* __restrict__ h1fh0, short* __restrict__ h1fl0,
    short* __restrict__ h1fh1, short* __restrict__ h1fl1,
    float* __restrict__ H0f, float* __restrict__ H1f,
    unsigned* __restrict__ sync)
{
    __shared__ float quad[4][4096];            // 64 KB
    __shared__ __align__(16) float sb[2][64];
    __shared__ float swin[192];
    __shared__ unsigned info[2];

    const int tid = threadIdx.x;
    const int bid = blockIdx.x;

    // ---- placement discovery: claim a slot on this block's physical XCD, then
    // verify every XCD got exactly 32 blocks. Garbage hwreg value or uneven
    // placement -> verification fails -> fall back to the proven R6 path.
    if (tid == 0) {
        unsigned xcd;
        asm volatile("s_getreg_b32 %0, hwreg(20, 0, 4)" : "=s"(xcd));  // HW_REG_XCC_ID
        xcd &= 7u;
        unsigned slot = __hip_atomic_fetch_add(&sync[384 + xcd], 1u,
                          __ATOMIC_RELAXED, __HIP_MEMORY_SCOPE_AGENT);
        unsigned a = __hip_atomic_fetch_add(&sync[416], 1u,
                          __ATOMIC_RELAXED, __HIP_MEMORY_SCOPE_AGENT);
        if (a == (unsigned)(NBLK - 1))
            __hip_atomic_store(&sync[448], 1u, __ATOMIC_RELAXED, __HIP_MEMORY_SCOPE_AGENT);
        while (__hip_atomic_load(&sync[448], __ATOMIC_RELAXED,
                                 __HIP_MEMORY_SCOPE_AGENT) < 1u)
            __builtin_amdgcn_s_sleep(2);
        bool good = (slot < 32u);
        #pragma unroll
        for (int xx = 0; xx < 8; ++xx)
            good = good && (__hip_atomic_load(&sync[384 + xx], __ATOMIC_RELAXED,
                                              __HIP_MEMORY_SCOPE_AGENT) == 32u);
        info[0] = good ? (0x100u | xcd) : 0u;
        info[1] = slot;
    }
    __syncthreads();
    const bool good = (info[0] & 0x100u) != 0u;
    const int rblk = good ? (int)(info[0] & 7u) : (bid >> 5);
    const int jt   = good ? (int)info[1]        : (bid & 31);

    if (good) {
        run_main<false>(tid, bid, rblk, jt, quad, sb, swin,
            W0h, W0l, W1h, W1l, WIh, WIl, Wih0, x,
            bih0, bhh0, bih1, bhh1, c0in,
            h0fh0, h0fl0, h0fh1, h0fl1, h1fh0, h1fl0, h1fh1, h1fl1,
            H0f, H1f, sync);
    } else {
        run_main<true>(tid, bid, rblk, jt, quad, sb, swin,
            W0h, W0l, W1h, W1l, WIh, WIl, Wih0, x,
            bih0, bhh0, bih1, bhh1, c0in,
            h0fh0, h0fl0, h0fh1, h0fl1, h1fh0, h1fl0, h1fh1, h1fl1,
            H0f, H1f, sync);
    }
}

// td[b][s] = btd[s] + cat(h0T,h1T)[b][:] . Wtd[s][:]  (validated R1/R2)
__global__ __launch_bounds__(256)
void td_kernel(const float* __restrict__ h0T, const float* __restrict__ h1T,
               const float* __restrict__ Wtd, const float* __restrict__ btd,
               float* __restrict__ td)
{
    __shared__ float a_lds[TM][TK + 1];
    __shared__ float b_lds[TN][TK + 1];
    const int t = threadIdx.x;
    const int nl = t & 31;
    const int mq = t >> 5;
    const int n0 = blockIdx.x * TN;
    const int m0 = blockIdx.y * TM;
    float acc[4] = {0.f, 0.f, 0.f, 0.f};

    for (int k0 = 0; k0 < 2 * HH; k0 += TK) {
        const float* src = (k0 < HH) ? h0T : h1T;
        int kb = k0 & (HH - 1);
        #pragma unroll
        for (int i = 0; i < (TM * TK) / 256; ++i) {
            int idx = t + i * 256;
            int r = idx >> 5, kk = idx & 31;
            a_lds[r][kk] = src[(size_t)(m0 + r) * HH + kb + kk];
        }
        #pragma unroll
        for (int i = 0; i < (TN * TK) / 256; ++i) {
            int idx = t + i * 256;
            int jn = idx >> 5, kk = idx & 31;
            b_lds[jn][kk] = Wtd[(size_t)(n0 + jn) * (2 * HH) + k0 + kk];
        }
        __syncthreads();
        #pragma unroll
        for (int kk = 0; kk < TK; ++kk) {
            float bv = b_lds[nl][kk];
            #pragma unroll
            for (int rr = 0; rr < 4; ++rr)
                acc[rr] = fmaf(a_lds[mq * 4 + rr][kk], bv, acc[rr]);
        }
        __syncthreads();
    }
    #pragma unroll
    for (int rr = 0; rr < 4; ++rr)
        td[(size_t)(m0 + mq * 4 + rr) * TDN + n0 + nl] = acc[rr] + btd[n0 + nl];
}

__global__ __launch_bounds__(256)
void fc_kernel(const float* __restrict__ td,
               const float* __restrict__ Wfc1, const float* __restrict__ bfc1,
               const float* __restrict__ Wfc2, const float* __restrict__ bfc2,
               float* __restrict__ out)
{
    __shared__ float td_lds[32][TDN];
    __shared__ float f1_lds[32][FC1N];
    const int t = threadIdx.x;
    const int r0 = blockIdx.x * 32;

    #pragma unroll
    for (int i = 0; i < (32 * TDN) / 256; ++i) {
        int idx = t + i * 256;
        int r = idx >> 8, k = idx & 255;
        td_lds[r][k] = td[(size_t)(r0 + r) * TDN + k];
    }
    __syncthreads();

    for (int idx = t; idx < 32 * FC1N; idx += 256) {
        int r = idx / FC1N, o = idx % FC1N;
        float s = bfc1[o];
        for (int k = 0; k < TDN; ++k) s = fmaf(td_lds[r][k], Wfc1[o * TDN + k], s);
        f1_lds[r][o] = fmaxf(s, 0.0f);
    }
    __syncthreads();

    for (int idx = t; idx < 32 * OUTN; idx += 256) {
        int r = idx / OUTN, o = idx % OUTN;
        float s = bfc2[o];
        for (int k = 0; k < FC1N; ++k) s = fmaf(f1_lds[r][k], Wfc2[o * FC1N + k], s);
        out[(size_t)(r0 + r) * OUTN + o] = s;
    }
}

extern "C" void kernel_launch(void* const* d_in, const int* in_sizes, int n_in,
                              void* d_out, int out_size, void* d_ws, size_t ws_size,
                              hipStream_t stream)
{
    const float* x    = (const float*)d_in[0];
    const float* h0   = (const float*)d_in[1];
    const float* c0   = (const float*)d_in[2];
    const float* Wih0 = (const float*)d_in[3];
    const float* Whh0 = (const float*)d_in[4];
    const float* bih0 = (const float*)d_in[5];
    const float* bhh0 = (const float*)d_in[6];
    const float* Wih1 = (const float*)d_in[7];
    const float* Whh1 = (const float*)d_in[8];
    const float* bih1 = (const float*)d_in[9];
    const float* bhh1 = (const float*)d_in[10];
    const float* Wtd  = (const float*)d_in[11];
    const float* btd  = (const float*)d_in[12];
    const float* Wfc1 = (const float*)d_in[13];
    const float* bfc1 = (const float*)d_in[14];
    const float* Wfc2 = (const float*)d_in[15];
    const float* bfc2 = (const float*)d_in[16];
    float* out = (float*)d_out;

    const size_t WSZ = (size_t)4 * HH * HH;      // 1M elems
    const size_t HFR = (size_t)32 * 16 * 64 * 8; // 262144 elems
    const size_t HSZ = (size_t)BB * HH;

    char* pp = (char*)d_ws;
    short* W0h = (short*)pp; pp += WSZ * 2;
    short* W0l = (short*)pp; pp += WSZ * 2;
    short* W1h = (short*)pp; pp += WSZ * 2;
    short* W1l = (short*)pp; pp += WSZ * 2;
    short* WIh = (short*)pp; pp += WSZ * 2;
    short* WIl = (short*)pp; pp += WSZ * 2;
    short* h0fh0 = (short*)pp; pp += HFR * 2;
    short* h0fl0 = (short*)pp; pp += HFR * 2;
    short* h0fh1 = (short*)pp; pp += HFR * 2;
    short* h0fl1 = (short*)pp; pp += HFR * 2;
    short* h1fh0 = (short*)pp; pp += HFR * 2;
    short* h1fl0 = (short*)pp; pp += HFR * 2;
    short* h1fh1 = (short*)pp; pp += HFR * 2;
    short* h1fl1 = (short*)pp; pp += HFR * 2;
    float* H0f = (float*)pp; pp += HSZ * 4;
    float* H1f = (float*)pp; pp += HSZ * 4;
    float* TD  = (float*)pp; pp += (size_t)BB * TDN * 4;
    unsigned* sync = (unsigned*)pp; pp += SYNC_WORDS * 4;

    cvt_wfrag<<<dim3(512), dim3(256), 0, stream>>>(Whh0, W0h, W0l);
    cvt_wfrag<<<dim3(512), dim3(256), 0, stream>>>(Whh1, W1h, W1l);
    cvt_wfrag<<<dim3(512), dim3(256), 0, stream>>>(Wih1, WIh, WIl);
    cvt_hfrag<<<dim3(128), dim3(256), 0, stream>>>(h0,        h0fh0, h0fl0);   // layer0 init -> parity 0
    cvt_hfrag<<<dim3(128), dim3(256), 0, stream>>>(h0 + HSZ,  h1fh1, h1fl1);   // layer1 init -> parity 1
    zero_sync<<<dim3(SYNC_WORDS / 256), dim3(256), 0, stream>>>(sync);

    lstm_persist<<<dim3(NBLK), dim3(512), 0, stream>>>(
        W0h, W0l, W1h, W1l, WIh, WIl,
        Wih0, x, bih0, bhh0, bih1, bhh1, c0,
        h0fh0, h0fl0, h0fh1, h0fl1,
        h1fh0, h1fl0, h1fh1, h1fl1,
        H0f, H1f, sync);

    const dim3 gtd(TDN / TN, BB / TM);
    td_kernel<<<gtd, dim3(256), 0, stream>>>(H0f, H1f, Wtd, btd, TD);
    fc_kernel<<<dim3(BB / 32), dim3(256), 0, stream>>>(TD, Wfc1, bfc1, Wfc2, bfc2, out);

    (void)in_sizes; (void)n_in; (void)out_size; (void)ws_size;
}